// Round 22
// baseline (177.209 us; speedup 1.0000x reference)
//
#include <hip/hip_runtime.h>
#include <math.h>

#define F_NUM 8
#define N_AT 2048
#define E_EDGE 32768
#define FE (F_NUM*E_EDGE)   // 262144 base edges
#define FN (F_NUM*N_AT)     // 16384 atoms
#define CAP 72              // per-atom incidence capacity (avg 32, Poisson)
#define PI_F 3.14159265358979f

#if defined(__has_builtin)
#if __has_builtin(__builtin_amdgcn_fdot2)
#define HAS_FDOT2 1
#endif
#endif

typedef _Float16 h2 __attribute__((ext_vector_type(2)));

// XCD-aware swizzle: frame-major work chunks land on one XCD (frame f -> XCD f)
#define XSWZ(bid, G) (((bid) & 7) * ((G) >> 3) + ((bid) >> 3))

__device__ __forceinline__ unsigned short f2b(float x) {
    unsigned int u = __float_as_uint(x);
    u += 0x8000u;
    return (unsigned short)(u >> 16);
}
__device__ __forceinline__ float blo(unsigned int u) { return __uint_as_float(u << 16); }
__device__ __forceinline__ float bhi(unsigned int u) { return __uint_as_float(u & 0xffff0000u); }
__device__ __forceinline__ float b2f(unsigned short u) { return __uint_as_float((unsigned)u << 16); }

__device__ __forceinline__ unsigned f2h(float x) {
    union { _Float16 h; unsigned short u; } cv;
    cv.h = (_Float16)x;
    return (unsigned)cv.u;
}
__device__ __forceinline__ h2 u2h2(unsigned u) {
    union { unsigned u; h2 h; } cv;
    cv.u = u;
    return cv.h;
}
__device__ __forceinline__ float dot8h(uint4 q, const h2* w) {
#ifdef HAS_FDOT2
    float a = __builtin_amdgcn_fdot2(u2h2(q.x), w[0], 0.f, false);
    a = __builtin_amdgcn_fdot2(u2h2(q.y), w[1], a, false);
    a = __builtin_amdgcn_fdot2(u2h2(q.z), w[2], a, false);
    a = __builtin_amdgcn_fdot2(u2h2(q.w), w[3], a, false);
    return a;
#else
    h2 a0 = u2h2(q.x), a1 = u2h2(q.y), a2 = u2h2(q.z), a3 = u2h2(q.w);
    return (float)a0.x*(float)w[0].x + (float)a0.y*(float)w[0].y
         + (float)a1.x*(float)w[1].x + (float)a1.y*(float)w[1].y
         + (float)a2.x*(float)w[2].x + (float)a2.y*(float)w[2].y
         + (float)a3.x*(float)w[3].x + (float)a3.y*(float)w[3].y;
#endif
}
__device__ __forceinline__ void prep_wr(const float* __restrict__ Wrad_l, int c, h2* wr) {
#pragma unroll
    for (int bb = 0; bb < 4; bb++) {
        h2 t;
        t.x = (_Float16)Wrad_l[(2*bb)   * 128 + c * 4];
        t.y = (_Float16)Wrad_l[(2*bb+1) * 128 + c * 4];
        wr[bb] = t;
    }
}

// ---------------- prologue: zero cnt (16 blocks) + compute g2 (1 block) ----------------
__global__ __launch_bounds__(256) void k_zg(
    int4* __restrict__ cnt4, const float* __restrict__ w_out,
    const float* __restrict__ Wmix2, float* __restrict__ g2)
{
    int bid = blockIdx.x;
    if (bid < 16) {
        cnt4[bid * 256 + threadIdx.x] = make_int4(0, 0, 0, 0);
    } else if (threadIdx.x < 32) {
        int c = threadIdx.x;
        float acc = 0.f;
#pragma unroll
        for (int d = 0; d < 32; d++) acc += w_out[d] * Wmix2[c * 32 + d];
        g2[c] = acc;
    }
}

// Incidence record (32 B):
//   rec[2j]   = { nb, B.x, B.y, B.z }     nb = (u<<3)|(sign<<2)|type
//   rec[2j+1] = { B.w, ux|uy, uz|0, dEdr }  unit f16x3 sign-applied; .w filled by k_force_e
// Edge record edat[k] = { (a<<2)|ta, (b<<2)|tb, ja, jb }

// ---------------- edges ----------------
__global__ __launch_bounds__(256) void k_edges(
    const float* __restrict__ pos, const int* __restrict__ eidx,
    const float* __restrict__ cell, const int* __restrict__ co_p,
    const int* __restrict__ at,
    uint4* __restrict__ dbq, uint4* __restrict__ edat,
    int* __restrict__ cnt, uint4* __restrict__ rec)
{
    int bid = XSWZ(blockIdx.x, FE / 256);
    int k = bid * 256 + threadIdx.x;
    int f = k >> 15;
    int e = k & (E_EDGE - 1);
    int a = eidx[f * 2 * E_EDGE + e] + f * N_AT;
    int b = eidx[f * 2 * E_EDGE + E_EDGE + e] + f * N_AT;
    int ta = at[a], tb = at[b];
    float co = (float)co_p[0];

    float vec[3];
#pragma unroll
    for (int d = 0; d < 3; d++) {
        float v  = pos[3 * b + d] - pos[3 * a + d];
        float cl = cell[3 * f + d];
        float sh = cl * ((v < -co ? 1.f : 0.f) - (v > co ? 1.f : 0.f));
        vec[d] = v + sh;
    }
    float r2   = vec[0]*vec[0] + vec[1]*vec[1] + vec[2]*vec[2] + 1e-12f;
    float r    = sqrtf(r2);
    float rinv = 1.f / r;
    float ux = vec[0]*rinv, uy = vec[1]*rinv, uz = vec[2]*rinv;
    unsigned up01 = f2h(ux)  | (f2h(uy)  << 16);
    unsigned up2  = f2h(uz);
    unsigned un01 = f2h(-ux) | (f2h(-uy) << 16);
    unsigned un2  = f2h(-uz);

    float x = r * (1.f / 6.f);           // R_MAX = 6
    float env = 0.f, denv = 0.f;
    if (x < 1.f) {
        float x2 = x*x, x3 = x2*x, x5 = x2*x3, x6 = x5*x, x7 = x6*x, x8 = x7*x;
        env  = 1.f - 28.f*x6 + 48.f*x7 - 21.f*x8;
        denv = -168.f*x5 + 336.f*x6 - 168.f*x7;
    }
    float s1, c1;
    sincosf(PI_F * x, &s1, &c1);
    float sn = s1, cn = c1;
    const float C0 = 0.57735026919f;     // sqrt(2/6)
    float bs[8], db[8];
#pragma unroll
    for (int n = 1; n <= 8; n++) {
        float kn  = (float)n * PI_F * (1.f / 6.f);
        float bes = C0 * sn * rinv;
        bs[n-1] = bes * env;
        db[n-1] = C0 * rinv * (kn * cn - sn * rinv) * env + bes * denv * (1.f / 6.f);
        float sn2 = sn * c1 + cn * s1;
        float cn2 = cn * c1 - sn * s1;
        sn = sn2; cn = cn2;
    }
    uint4 B, D;
    B.x = f2h(bs[0]) | (f2h(bs[1]) << 16);
    B.y = f2h(bs[2]) | (f2h(bs[3]) << 16);
    B.z = f2h(bs[4]) | (f2h(bs[5]) << 16);
    B.w = f2h(bs[6]) | (f2h(bs[7]) << 16);
    D.x = f2h(db[0]) | (f2h(db[1]) << 16);
    D.y = f2h(db[2]) | (f2h(db[3]) << 16);
    D.z = f2h(db[4]) | (f2h(db[5]) << 16);
    D.w = f2h(db[6]) | (f2h(db[7]) << 16);
    dbq[k] = D;

    int sa = atomicAdd(&cnt[a], 1);
    unsigned ja = (unsigned)(FN * CAP);          // dump slot on overflow
    if (sa < CAP) {
        int j = a * CAP + sa;
        ja = (unsigned)j;
        rec[2*j]     = make_uint4((unsigned)((b << 3) | tb), B.x, B.y, B.z);
        rec[2*j + 1] = make_uint4(B.w, up01, up2, 0);
    }
    int sb = atomicAdd(&cnt[b], 1);
    unsigned jb = (unsigned)(FN * CAP);
    if (sb < CAP) {
        int j = b * CAP + sb;
        jb = (unsigned)j;
        rec[2*j]     = make_uint4((unsigned)((a << 3) | 4 | ta), B.x, B.y, B.z);
        rec[2*j + 1] = make_uint4(B.w, un01, un2, 0);
    }
    edat[k] = make_uint4((unsigned)((a << 2) | ta), (unsigned)((b << 2) | tb), ja, jb);
}

#define LOADREC(J, NB, B)                                    \
    {                                                        \
        uint4 ra = rec[2*(J)], rb = rec[2*(J)+1];            \
        NB = (int)ra.x;                                      \
        B  = make_uint4(ra.y, ra.z, ra.w, rb.x);             \
    }

// ---------------- L0: group-walk form, LDS embed table, shuffle mix ----------------
__global__ __launch_bounds__(512) void k_L0(
    const float* __restrict__ W_embed, unsigned short* __restrict__ soq,
    const int* __restrict__ cnt, const uint4* __restrict__ rec,
    const float* __restrict__ Wrad_l, const float* __restrict__ Wmix_l,
    const int* __restrict__ at)
{
    __shared__ float We[128];
    int t = threadIdx.x;
    if (t < 128) We[t] = W_embed[t];
    int bid = XSWZ(blockIdx.x, FN / 64);
    int g = t >> 5, c = t & 31;
    int abase = bid * 64;
    h2 wr[4];
    prep_wr(Wrad_l, c, wr);
    float wv[32];
#pragma unroll
    for (int cc = 0; cc < 32; ++cc) wv[cc] = Wmix_l[cc * 32 + c];  // Wmix[cc][c]
    __syncthreads();

    for (int i = 0; i < 4; ++i) {
        int n = abase + g * 4 + i;
        int cn = min(cnt[n], CAP);
        int j = n * CAP, j1 = n * CAP + cn;
        float A = 0.f;
        for (; j + 3 < j1; j += 4) {
            int n0, n1, n2, n3;
            uint4 b0, b1, b2, b3;
            LOADREC(j, n0, b0) LOADREC(j+1, n1, b1) LOADREC(j+2, n2, b2) LOADREC(j+3, n3, b3)
            A += dot8h(b0, wr) * We[(n0 & 3) * 32 + c] + dot8h(b1, wr) * We[(n1 & 3) * 32 + c]
               + dot8h(b2, wr) * We[(n2 & 3) * 32 + c] + dot8h(b3, wr) * We[(n3 & 3) * 32 + c];
        }
        for (; j < j1; ++j) {
            int n0; uint4 b0;
            LOADREC(j, n0, b0)
            A += dot8h(b0, wr) * We[(n0 & 3) * 32 + c];
        }
        float acc = 0.f;
#pragma unroll
        for (int cc = 0; cc < 32; ++cc) acc += __shfl(A, cc, 32) * wv[cc];
        soq[n * 32 + c] = f2b(We[at[n] * 32 + c] + acc);
    }
}

// ======== STAGED WALKS: frame feature table (128 KB) in LDS; 256 blocks x 512 thr ========

// ---------------- L1 staged ----------------
__global__ __launch_bounds__(512) void k_L1s(
    const unsigned short* __restrict__ slq, unsigned short* __restrict__ soq,
    const int* __restrict__ cnt, const uint4* __restrict__ rec,
    const float* __restrict__ Wrad_l, const float* __restrict__ Wmix_l)
{
    extern __shared__ unsigned short feat[];   // 2048*32 = 128 KB
    int t = threadIdx.x;
    int bid = XSWZ(blockIdx.x, 256);
    int frame = bid >> 5;
    int fat = frame * N_AT;
    int abase = fat + (bid & 31) * 64;
    const uint4* src = (const uint4*)(slq + (size_t)fat * 32);
    uint4* dst = (uint4*)feat;
#pragma unroll
    for (int it = 0; it < 16; ++it) dst[t + it * 512] = src[t + it * 512];
    int g = t >> 5, c = t & 31;
    h2 wr[4];
    prep_wr(Wrad_l, c, wr);
    float wv[32];
#pragma unroll
    for (int cc = 0; cc < 32; ++cc) wv[cc] = Wmix_l[cc * 32 + c];  // Wmix[cc][c]
    __syncthreads();

    for (int i = 0; i < 4; ++i) {
        int n = abase + g * 4 + i;
        int cn = min(cnt[n], CAP);
        int j = n * CAP, j1 = n * CAP + cn;
        float A = 0.f;
        for (; j + 3 < j1; j += 4) {
            int n0, n1, n2, n3;
            uint4 b0, b1, b2, b3;
            LOADREC(j, n0, b0) LOADREC(j+1, n1, b1) LOADREC(j+2, n2, b2) LOADREC(j+3, n3, b3)
            float sv0 = b2f(feat[((n0 >> 3) - fat) * 32 + c]);
            float sv1 = b2f(feat[((n1 >> 3) - fat) * 32 + c]);
            float sv2 = b2f(feat[((n2 >> 3) - fat) * 32 + c]);
            float sv3 = b2f(feat[((n3 >> 3) - fat) * 32 + c]);
            A += dot8h(b0, wr) * sv0 + dot8h(b1, wr) * sv1
               + dot8h(b2, wr) * sv2 + dot8h(b3, wr) * sv3;
        }
        for (; j < j1; ++j) {
            int n0; uint4 b0;
            LOADREC(j, n0, b0)
            A += dot8h(b0, wr) * b2f(feat[((n0 >> 3) - fat) * 32 + c]);
        }
        float acc = 0.f;
#pragma unroll
        for (int cc = 0; cc < 32; ++cc) acc += __shfl(A, cc, 32) * wv[cc];
        float base_s = b2f(feat[(n - fat) * 32 + c]);
        soq[n * 32 + c] = f2b(base_s + acc);
    }
}

// ---------------- L2E staged: energy partial + barS2 + barA1 ----------------
__global__ __launch_bounds__(512) void k_L2Es(
    const unsigned short* __restrict__ s2q,
    const int* __restrict__ cnt, const uint4* __restrict__ rec,
    const float* __restrict__ Wrad2, const float* __restrict__ Wmix1,
    const float* __restrict__ w_out, const float* __restrict__ g2,
    float* __restrict__ barS2, unsigned short* __restrict__ ba1q, float* __restrict__ epart)
{
    extern __shared__ unsigned short feat[];
    int t = threadIdx.x;
    int bid = XSWZ(blockIdx.x, 256);
    int frame = bid >> 5;
    int fat = frame * N_AT;
    int abase = fat + (bid & 31) * 64;
    const uint4* src = (const uint4*)(s2q + (size_t)fat * 32);
    uint4* dst = (uint4*)feat;
#pragma unroll
    for (int it = 0; it < 16; ++it) dst[t + it * 512] = src[t + it * 512];
    int g = t >> 5, c = t & 31;
    h2 wr[4];
    prep_wr(Wrad2, c, wr);
    float wv[32];
#pragma unroll
    for (int d = 0; d < 32; ++d) wv[d] = Wmix1[c * 32 + d];   // Wmix1[c][d]
    float woc = w_out[c], g2c = g2[c];
    __syncthreads();

    for (int i = 0; i < 4; ++i) {
        int n = abase + g * 4 + i;
        int cn = min(cnt[n], CAP);
        int j = n * CAP, j1 = n * CAP + cn;
        float A = 0.f, S = 0.f;
        for (; j + 3 < j1; j += 4) {
            int n0, n1, n2, n3;
            uint4 b0, b1, b2, b3;
            LOADREC(j, n0, b0) LOADREC(j+1, n1, b1) LOADREC(j+2, n2, b2) LOADREC(j+3, n3, b3)
            float r0 = dot8h(b0, wr), r1 = dot8h(b1, wr), r2 = dot8h(b2, wr), r3 = dot8h(b3, wr);
            A += r0 * b2f(feat[((n0 >> 3) - fat) * 32 + c]) + r1 * b2f(feat[((n1 >> 3) - fat) * 32 + c])
               + r2 * b2f(feat[((n2 >> 3) - fat) * 32 + c]) + r3 * b2f(feat[((n3 >> 3) - fat) * 32 + c]);
            S += r0 + r1 + r2 + r3;
        }
        for (; j < j1; ++j) {
            int n0; uint4 b0;
            LOADREC(j, n0, b0)
            float rr = dot8h(b0, wr);
            A += rr * b2f(feat[((n0 >> 3) - fat) * 32 + c]);
            S += rr;
        }
        float s2n = b2f(feat[(n - fat) * 32 + c]);
        float te = s2n * woc + A * g2c;
#pragma unroll
        for (int o = 1; o <= 16; o <<= 1) te += __shfl_xor(te, o, 32);
        if (c == 0) epart[n] = te;
        float bs2 = woc + g2c * S;
        barS2[n * 32 + c] = bs2;
        float acc = 0.f;
#pragma unroll
        for (int d = 0; d < 32; ++d) acc += __shfl(bs2, d, 32) * wv[d];
        ba1q[n * 32 + c] = f2b(acc);
    }
}

// ---------------- B1F staged: barS1 -> barA0 -> pk ----------------
// pk layout: x = s1 | s2<<16 ; y = ba0 | ba1<<16
__global__ __launch_bounds__(512) void k_B1Fs(
    const unsigned short* __restrict__ ba1q, const float* __restrict__ barS2,
    const unsigned short* __restrict__ s1q, const unsigned short* __restrict__ s2q,
    const int* __restrict__ cnt, const uint4* __restrict__ rec,
    const float* __restrict__ Wrad1, const float* __restrict__ Wmix0,
    uint2* __restrict__ pk)
{
    extern __shared__ unsigned short feat[];
    int t = threadIdx.x;
    int bid = XSWZ(blockIdx.x, 256);
    int frame = bid >> 5;
    int fat = frame * N_AT;
    int abase = fat + (bid & 31) * 64;
    const uint4* src = (const uint4*)(ba1q + (size_t)fat * 32);
    uint4* dst = (uint4*)feat;
#pragma unroll
    for (int it = 0; it < 16; ++it) dst[t + it * 512] = src[t + it * 512];
    int g = t >> 5, c = t & 31;
    h2 wr[4];
    prep_wr(Wrad1, c, wr);
    float wv[32];
#pragma unroll
    for (int d = 0; d < 32; ++d) wv[d] = Wmix0[c * 32 + d];   // Wmix0[c][d]
    __syncthreads();

    for (int i = 0; i < 4; ++i) {
        int n = abase + g * 4 + i;
        int cn = min(cnt[n], CAP);
        int j = n * CAP, j1 = n * CAP + cn;
        float A = 0.f;
        for (; j + 3 < j1; j += 4) {
            int n0, n1, n2, n3;
            uint4 b0, b1, b2, b3;
            LOADREC(j, n0, b0) LOADREC(j+1, n1, b1) LOADREC(j+2, n2, b2) LOADREC(j+3, n3, b3)
            A += dot8h(b0, wr) * b2f(feat[((n0 >> 3) - fat) * 32 + c])
               + dot8h(b1, wr) * b2f(feat[((n1 >> 3) - fat) * 32 + c])
               + dot8h(b2, wr) * b2f(feat[((n2 >> 3) - fat) * 32 + c])
               + dot8h(b3, wr) * b2f(feat[((n3 >> 3) - fat) * 32 + c]);
        }
        for (; j < j1; ++j) {
            int n0; uint4 b0;
            LOADREC(j, n0, b0)
            A += dot8h(b0, wr) * b2f(feat[((n0 >> 3) - fat) * 32 + c]);
        }
        int n32c = n * 32 + c;
        float bs1 = barS2[n32c] + A;
        float acc = 0.f;
#pragma unroll
        for (int d = 0; d < 32; ++d) acc += __shfl(bs1, d, 32) * wv[d];
        uint2 v;
        v.x = (unsigned)s1q[n32c] | ((unsigned)s2q[n32c] << 16);
        v.y = (unsigned)f2b(acc)  | ((unsigned)feat[(n - fat) * 32 + c] << 16);
        pk[n32c] = v;
    }
}

// ---------------- force pass 1: r18 preloaded form; writes dEdr into rec[2j+1].w of both slots ----------------
#define EPG 8   // edges per 32-lane group
__global__ __launch_bounds__(256, 4) void k_force_e(
    const uint2* __restrict__ pk, const float* __restrict__ g2,
    const uint4* __restrict__ dbq, const uint4* __restrict__ edat,
    const float* __restrict__ W_embed, const float* __restrict__ W_rad,
    unsigned* __restrict__ recw)      // = (unsigned*)rec; slot .w of rec[2j+1] at recw[8j+7]
{
    __shared__ float We[128];
    int t = threadIdx.x;
    if (t < 128) We[t] = W_embed[t];
    int bid = XSWZ(blockIdx.x, FE / (8 * EPG));
    int g = t >> 5;
    int c = t & 31;
    h2 wr0[4], wr1[4], wr2[4];
    prep_wr(W_rad + 0 * 1024, c, wr0);
    prep_wr(W_rad + 1 * 1024, c, wr1);
    prep_wr(W_rad + 2 * 1024, c, wr2);
    float g2c = g2[c];
    __syncthreads();

    int kbase = (bid * 8 + g) * EPG;
    uint4 e2a[EPG];
#pragma unroll
    for (int kk = 0; kk < EPG; ++kk) e2a[kk] = edat[kbase + kk];
    uint2 qa[EPG], qb[EPG];
    uint4 dd[EPG];
#pragma unroll
    for (int kk = 0; kk < EPG; ++kk) {
        qa[kk] = pk[(e2a[kk].x >> 2) * 32 + c];
        qb[kk] = pk[(e2a[kk].y >> 2) * 32 + c];
        dd[kk] = dbq[kbase + kk];
    }
#pragma unroll
    for (int kk = 0; kk < EPG; ++kk) {
        uint4 e2 = e2a[kk];
        float s0a = We[(e2.x & 3) * 32 + c];
        float s0b = We[(e2.y & 3) * 32 + c];
        float dR0 = dot8h(dd[kk], wr0), dR1 = dot8h(dd[kk], wr1), dR2 = dot8h(dd[kk], wr2);
        float tc = dR0 * (blo(qa[kk].y) * s0b + blo(qb[kk].y) * s0a)
                 + dR1 * (bhi(qa[kk].y) * blo(qb[kk].x) + bhi(qb[kk].y) * blo(qa[kk].x))
                 + dR2 * g2c * (bhi(qa[kk].x) + bhi(qb[kk].x));
#pragma unroll
        for (int o = 1; o <= 16; o <<= 1) tc += __shfl_xor(tc, o, 32);
        if (c == 0) recw[8 * (size_t)e2.z + 7] = __float_as_uint(tc);
        else if (c == 1) recw[8 * (size_t)e2.w + 7] = __float_as_uint(tc);
    }
}

// ---------------- fused: force pass 2 (one sequential 16B read/visit) + energy reduce ----------------
__global__ __launch_bounds__(256, 8) void k_fgat(
    const int* __restrict__ cnt, const uint4* __restrict__ rec,
    const float* __restrict__ epart, float* __restrict__ out)
{
    if (blockIdx.x >= FN / 8) {
        __shared__ float sm[256];
        int f = blockIdx.x - FN / 8, t = threadIdx.x;
        float a = 0.f;
        for (int i = t; i < N_AT; i += 256) a += epart[f * N_AT + i];
        sm[t] = a;
        __syncthreads();
        for (int s = 128; s; s >>= 1) {
            if (t < s) sm[t] += sm[t + s];
            __syncthreads();
        }
        if (t == 0) out[f] = sm[0];
        return;
    }
    int t = threadIdx.x;
    int bid = XSWZ(blockIdx.x, FN / 8);
    int g = t >> 5, lane = t & 31;
    int n = bid * 8 + g;
    int cn = min(cnt[n], CAP);
    int base = n * CAP;
    float Fx = 0.f, Fy = 0.f, Fz = 0.f;
    for (int j = base + lane; j < base + cn; j += 32) {
        uint4 r1 = rec[2 * j + 1];            // { B.w, ux|uy, uz, dEdr }
        float d = __uint_as_float(r1.w);
        h2 uxy = u2h2(r1.y);
        Fx += d * (float)uxy.x;
        Fy += d * (float)uxy.y;
        Fz += d * (float)u2h2(r1.z).x;
    }
#pragma unroll
    for (int o = 1; o <= 16; o <<= 1) {
        Fx += __shfl_xor(Fx, o, 32);
        Fy += __shfl_xor(Fy, o, 32);
        Fz += __shfl_xor(Fz, o, 32);
    }
    if (lane == 0) {
        out[8 + n * 3 + 0] = Fx;
        out[8 + n * 3 + 1] = Fy;
        out[8 + n * 3 + 2] = Fz;
    }
}

extern "C" void kernel_launch(void* const* d_in, const int* in_sizes, int n_in,
                              void* d_out, int out_size, void* d_ws, size_t ws_size,
                              hipStream_t stream)
{
    const float* pos     = (const float*)d_in[0];
    const int*   eidx    = (const int*)  d_in[1];
    const float* cell    = (const float*)d_in[2];
    const int*   at      = (const int*)  d_in[3];
    const float* W_embed = (const float*)d_in[4];
    const float* W_rad   = (const float*)d_in[5];
    const float* W_mix   = (const float*)d_in[6];
    const float* w_out   = (const float*)d_in[7];
    const int*   co      = (const int*)  d_in[8];

    char* p = (char*)d_ws;
    auto carve = [&](size_t bytes) -> char* {
        char* r = p;
        p += (bytes + 255) & ~(size_t)255;
        return r;
    };
    uint4*          dbq    = (uint4*)          carve((size_t)FE * 16);
    uint4*          edat   = (uint4*)          carve((size_t)FE * 16);
    unsigned short* s1q    = (unsigned short*) carve((size_t)FN * 32 * 2);
    unsigned short* s2q    = (unsigned short*) carve((size_t)FN * 32 * 2);
    unsigned short* ba1q   = (unsigned short*) carve((size_t)FN * 32 * 2);
    float*          barS2  = (float*)          carve((size_t)FN * 32 * 4);
    uint2*          pk     = (uint2*)          carve((size_t)FN * 32 * 8);
    float*          g2     = (float*)          carve(32 * 4);
    float*          epart  = (float*)          carve((size_t)FN * 4);
    int*            cnt    = (int*)            carve((size_t)FN * 4);
    uint4*          rec    = (uint4*)          carve((size_t)(FN * CAP + 1) * 32);  // +1 dump slot

    const size_t SMEM = (size_t)N_AT * 32 * 2;   // 128 KiB frame feature table

    // prologue: zero cnt (16 blocks) + g2 (1 block)
    k_zg<<<17, 256, 0, stream>>>((int4*)cnt, w_out, W_mix + 2 * 1024, g2);

    k_edges<<<FE / 256, 256, 0, stream>>>(pos, eidx, cell, co, at, dbq, edat, cnt, rec);

    // forward
    k_L0<<<FN / 64, 512, 0, stream>>>(W_embed, s1q, cnt, rec,
                                      W_rad + 0 * 1024, W_mix + 0 * 1024, at);
    k_L1s<<<256, 512, SMEM, stream>>>(s1q, s2q, cnt, rec,
                                      W_rad + 1 * 1024, W_mix + 1 * 1024);
    // layer 2 + energy partials + barS2 + barA1 (staged)
    k_L2Es<<<256, 512, SMEM, stream>>>(s2q, cnt, rec, W_rad + 2 * 1024,
                                       W_mix + 1 * 1024, w_out, g2, barS2, ba1q, epart);
    // backward l=1 + barA0 + pack (staged)
    k_B1Fs<<<256, 512, SMEM, stream>>>(ba1q, barS2, s1q, s2q, cnt, rec,
                                       W_rad + 1 * 1024, W_mix + 0 * 1024, pk);
    // forces pass 1 (preloaded edge-parallel -> dEdr into rec.w of both visit slots)
    k_force_e<<<FE / (8 * EPG), 256, 0, stream>>>(pk, g2, dbq, edat, W_embed, W_rad,
                                                  (unsigned*)rec);
    // forces pass 2 (sequential single-read) + energy reduce, fused
    k_fgat<<<FN / 8 + F_NUM, 256, 0, stream>>>(cnt, rec, epart, (float*)d_out);
}

// Round 23
// 174.846 us; speedup vs baseline: 1.0135x; 1.0135x over previous
//
#include <hip/hip_runtime.h>
#include <math.h>

#define F_NUM 8
#define N_AT 2048
#define E_EDGE 32768
#define FE (F_NUM*E_EDGE)   // 262144 base edges
#define FN (F_NUM*N_AT)     // 16384 atoms
#define CAP 72              // per-atom incidence capacity (avg 32, Poisson)
#define PI_F 3.14159265358979f

#if defined(__has_builtin)
#if __has_builtin(__builtin_amdgcn_fdot2)
#define HAS_FDOT2 1
#endif
#endif

typedef _Float16 h2 __attribute__((ext_vector_type(2)));

// XCD-aware swizzle: frame-major work chunks land on one XCD (frame f -> XCD f)
#define XSWZ(bid, G) (((bid) & 7) * ((G) >> 3) + ((bid) >> 3))

__device__ __forceinline__ unsigned short f2b(float x) {
    unsigned int u = __float_as_uint(x);
    u += 0x8000u;
    return (unsigned short)(u >> 16);
}
__device__ __forceinline__ float blo(unsigned int u) { return __uint_as_float(u << 16); }
__device__ __forceinline__ float bhi(unsigned int u) { return __uint_as_float(u & 0xffff0000u); }
__device__ __forceinline__ float b2f(unsigned short u) { return __uint_as_float((unsigned)u << 16); }

__device__ __forceinline__ unsigned f2h(float x) {
    union { _Float16 h; unsigned short u; } cv;
    cv.h = (_Float16)x;
    return (unsigned)cv.u;
}
__device__ __forceinline__ h2 u2h2(unsigned u) {
    union { unsigned u; h2 h; } cv;
    cv.u = u;
    return cv.h;
}
__device__ __forceinline__ float dot8h(uint4 q, const h2* w) {
#ifdef HAS_FDOT2
    float a = __builtin_amdgcn_fdot2(u2h2(q.x), w[0], 0.f, false);
    a = __builtin_amdgcn_fdot2(u2h2(q.y), w[1], a, false);
    a = __builtin_amdgcn_fdot2(u2h2(q.z), w[2], a, false);
    a = __builtin_amdgcn_fdot2(u2h2(q.w), w[3], a, false);
    return a;
#else
    h2 a0 = u2h2(q.x), a1 = u2h2(q.y), a2 = u2h2(q.z), a3 = u2h2(q.w);
    return (float)a0.x*(float)w[0].x + (float)a0.y*(float)w[0].y
         + (float)a1.x*(float)w[1].x + (float)a1.y*(float)w[1].y
         + (float)a2.x*(float)w[2].x + (float)a2.y*(float)w[2].y
         + (float)a3.x*(float)w[3].x + (float)a3.y*(float)w[3].y;
#endif
}
__device__ __forceinline__ void prep_wr(const float* __restrict__ Wrad_l, int c, h2* wr) {
#pragma unroll
    for (int bb = 0; bb < 4; bb++) {
        h2 t;
        t.x = (_Float16)Wrad_l[(2*bb)   * 128 + c * 4];
        t.y = (_Float16)Wrad_l[(2*bb+1) * 128 + c * 4];
        wr[bb] = t;
    }
}

// ---------------- prologue: zero cnt (16 blocks) + compute g2 (1 block) ----------------
__global__ __launch_bounds__(256) void k_zg(
    int4* __restrict__ cnt4, const float* __restrict__ w_out,
    const float* __restrict__ Wmix2, float* __restrict__ g2)
{
    int bid = blockIdx.x;
    if (bid < 16) {
        cnt4[bid * 256 + threadIdx.x] = make_int4(0, 0, 0, 0);
    } else if (threadIdx.x < 32) {
        int c = threadIdx.x;
        float acc = 0.f;
#pragma unroll
        for (int d = 0; d < 32; d++) acc += w_out[d] * Wmix2[c * 32 + d];
        g2[c] = acc;
    }
}

// Incidence record (32 B):
//   rec[2j]   = { nb, B.x, B.y, B.z }     nb = (u<<3)|(sign<<2)|type
//   rec[2j+1] = { B.w, ux|uy, uz|0, 0 }   unit as f16x3 with visit sign PRE-APPLIED

// ---------------- edges ----------------
__global__ __launch_bounds__(256) void k_edges(
    const float* __restrict__ pos, const int* __restrict__ eidx,
    const float* __restrict__ cell, const int* __restrict__ co_p,
    const int* __restrict__ at,
    uint4* __restrict__ dbq, uint2* __restrict__ ab, uint2* __restrict__ jsl,
    int* __restrict__ cnt, uint4* __restrict__ rec)
{
    int bid = XSWZ(blockIdx.x, FE / 256);
    int k = bid * 256 + threadIdx.x;
    int f = k >> 15;
    int e = k & (E_EDGE - 1);
    int a = eidx[f * 2 * E_EDGE + e] + f * N_AT;
    int b = eidx[f * 2 * E_EDGE + E_EDGE + e] + f * N_AT;
    int ta = at[a], tb = at[b];
    float co = (float)co_p[0];

    float vec[3];
#pragma unroll
    for (int d = 0; d < 3; d++) {
        float v  = pos[3 * b + d] - pos[3 * a + d];
        float cl = cell[3 * f + d];
        float sh = cl * ((v < -co ? 1.f : 0.f) - (v > co ? 1.f : 0.f));
        vec[d] = v + sh;
    }
    float r2   = vec[0]*vec[0] + vec[1]*vec[1] + vec[2]*vec[2] + 1e-12f;
    float r    = sqrtf(r2);
    float rinv = 1.f / r;
    float ux = vec[0]*rinv, uy = vec[1]*rinv, uz = vec[2]*rinv;
    unsigned up01 = f2h(ux)  | (f2h(uy)  << 16);
    unsigned up2  = f2h(uz);
    unsigned un01 = f2h(-ux) | (f2h(-uy) << 16);
    unsigned un2  = f2h(-uz);
    ab[k] = make_uint2((unsigned)((a << 2) | ta), (unsigned)((b << 2) | tb));

    float x = r * (1.f / 6.f);           // R_MAX = 6
    float env = 0.f, denv = 0.f;
    if (x < 1.f) {
        float x2 = x*x, x3 = x2*x, x5 = x2*x3, x6 = x5*x, x7 = x6*x, x8 = x7*x;
        env  = 1.f - 28.f*x6 + 48.f*x7 - 21.f*x8;
        denv = -168.f*x5 + 336.f*x6 - 168.f*x7;
    }
    float s1, c1;
    sincosf(PI_F * x, &s1, &c1);
    float sn = s1, cn = c1;
    const float C0 = 0.57735026919f;     // sqrt(2/6)
    float bs[8], db[8];
#pragma unroll
    for (int n = 1; n <= 8; n++) {
        float kn  = (float)n * PI_F * (1.f / 6.f);
        float bes = C0 * sn * rinv;
        bs[n-1] = bes * env;
        db[n-1] = C0 * rinv * (kn * cn - sn * rinv) * env + bes * denv * (1.f / 6.f);
        float sn2 = sn * c1 + cn * s1;
        float cn2 = cn * c1 - sn * s1;
        sn = sn2; cn = cn2;
    }
    uint4 B, D;
    B.x = f2h(bs[0]) | (f2h(bs[1]) << 16);
    B.y = f2h(bs[2]) | (f2h(bs[3]) << 16);
    B.z = f2h(bs[4]) | (f2h(bs[5]) << 16);
    B.w = f2h(bs[6]) | (f2h(bs[7]) << 16);
    D.x = f2h(db[0]) | (f2h(db[1]) << 16);
    D.y = f2h(db[2]) | (f2h(db[3]) << 16);
    D.z = f2h(db[4]) | (f2h(db[5]) << 16);
    D.w = f2h(db[6]) | (f2h(db[7]) << 16);
    dbq[k] = D;

    int sa = atomicAdd(&cnt[a], 1);
    unsigned ja = (unsigned)(FN * CAP);          // dump slot on overflow
    if (sa < CAP) {
        int j = a * CAP + sa;
        ja = (unsigned)j;
        rec[2*j]     = make_uint4((unsigned)((b << 3) | tb), B.x, B.y, B.z);
        rec[2*j + 1] = make_uint4(B.w, up01, up2, 0);
    }
    int sb = atomicAdd(&cnt[b], 1);
    unsigned jb = (unsigned)(FN * CAP);
    if (sb < CAP) {
        int j = b * CAP + sb;
        jb = (unsigned)j;
        rec[2*j]     = make_uint4((unsigned)((a << 3) | 4 | ta), B.x, B.y, B.z);
        rec[2*j + 1] = make_uint4(B.w, un01, un2, 0);
    }
    jsl[k] = make_uint2(ja, jb);
}

#define LOADREC(J, NB, B)                                    \
    {                                                        \
        uint4 ra = rec[2*(J)], rb = rec[2*(J)+1];            \
        NB = (int)ra.x;                                      \
        B  = make_uint4(ra.y, ra.z, ra.w, rb.x);             \
    }

// ---------------- L0: group-walk form, LDS embed table, shuffle mix ----------------
__global__ __launch_bounds__(512) void k_L0(
    const float* __restrict__ W_embed, unsigned short* __restrict__ soq,
    const int* __restrict__ cnt, const uint4* __restrict__ rec,
    const float* __restrict__ Wrad_l, const float* __restrict__ Wmix_l,
    const int* __restrict__ at)
{
    __shared__ float We[128];
    int t = threadIdx.x;
    if (t < 128) We[t] = W_embed[t];
    int bid = XSWZ(blockIdx.x, FN / 64);
    int g = t >> 5, c = t & 31;
    int abase = bid * 64;
    h2 wr[4];
    prep_wr(Wrad_l, c, wr);
    float wv[32];
#pragma unroll
    for (int cc = 0; cc < 32; ++cc) wv[cc] = Wmix_l[cc * 32 + c];  // Wmix[cc][c]
    __syncthreads();

    for (int i = 0; i < 4; ++i) {
        int n = abase + g * 4 + i;
        int cn = min(cnt[n], CAP);
        int j = n * CAP, j1 = n * CAP + cn;
        float A = 0.f;
        for (; j + 3 < j1; j += 4) {
            int n0, n1, n2, n3;
            uint4 b0, b1, b2, b3;
            LOADREC(j, n0, b0) LOADREC(j+1, n1, b1) LOADREC(j+2, n2, b2) LOADREC(j+3, n3, b3)
            A += dot8h(b0, wr) * We[(n0 & 3) * 32 + c] + dot8h(b1, wr) * We[(n1 & 3) * 32 + c]
               + dot8h(b2, wr) * We[(n2 & 3) * 32 + c] + dot8h(b3, wr) * We[(n3 & 3) * 32 + c];
        }
        for (; j < j1; ++j) {
            int n0; uint4 b0;
            LOADREC(j, n0, b0)
            A += dot8h(b0, wr) * We[(n0 & 3) * 32 + c];
        }
        float acc = 0.f;
#pragma unroll
        for (int cc = 0; cc < 32; ++cc) acc += __shfl(A, cc, 32) * wv[cc];
        soq[n * 32 + c] = f2b(We[at[n] * 32 + c] + acc);
    }
}

// ======== STAGED WALKS: frame feature table (128 KB) in LDS; 256 blocks x 512 thr ========

// ---------------- L1 staged ----------------
__global__ __launch_bounds__(512) void k_L1s(
    const unsigned short* __restrict__ slq, unsigned short* __restrict__ soq,
    const int* __restrict__ cnt, const uint4* __restrict__ rec,
    const float* __restrict__ Wrad_l, const float* __restrict__ Wmix_l)
{
    extern __shared__ unsigned short feat[];   // 2048*32 = 128 KB
    int t = threadIdx.x;
    int bid = XSWZ(blockIdx.x, 256);
    int frame = bid >> 5;
    int fat = frame * N_AT;
    int abase = fat + (bid & 31) * 64;
    const uint4* src = (const uint4*)(slq + (size_t)fat * 32);
    uint4* dst = (uint4*)feat;
#pragma unroll
    for (int it = 0; it < 16; ++it) dst[t + it * 512] = src[t + it * 512];
    int g = t >> 5, c = t & 31;
    h2 wr[4];
    prep_wr(Wrad_l, c, wr);
    float wv[32];
#pragma unroll
    for (int cc = 0; cc < 32; ++cc) wv[cc] = Wmix_l[cc * 32 + c];  // Wmix[cc][c]
    __syncthreads();

    for (int i = 0; i < 4; ++i) {
        int n = abase + g * 4 + i;
        int cn = min(cnt[n], CAP);
        int j = n * CAP, j1 = n * CAP + cn;
        float A = 0.f;
        for (; j + 3 < j1; j += 4) {
            int n0, n1, n2, n3;
            uint4 b0, b1, b2, b3;
            LOADREC(j, n0, b0) LOADREC(j+1, n1, b1) LOADREC(j+2, n2, b2) LOADREC(j+3, n3, b3)
            float sv0 = b2f(feat[((n0 >> 3) - fat) * 32 + c]);
            float sv1 = b2f(feat[((n1 >> 3) - fat) * 32 + c]);
            float sv2 = b2f(feat[((n2 >> 3) - fat) * 32 + c]);
            float sv3 = b2f(feat[((n3 >> 3) - fat) * 32 + c]);
            A += dot8h(b0, wr) * sv0 + dot8h(b1, wr) * sv1
               + dot8h(b2, wr) * sv2 + dot8h(b3, wr) * sv3;
        }
        for (; j < j1; ++j) {
            int n0; uint4 b0;
            LOADREC(j, n0, b0)
            A += dot8h(b0, wr) * b2f(feat[((n0 >> 3) - fat) * 32 + c]);
        }
        float acc = 0.f;
#pragma unroll
        for (int cc = 0; cc < 32; ++cc) acc += __shfl(A, cc, 32) * wv[cc];
        float base_s = b2f(feat[(n - fat) * 32 + c]);
        soq[n * 32 + c] = f2b(base_s + acc);
    }
}

// ---------------- L2E staged: energy partial + barS2 + barA1 ----------------
__global__ __launch_bounds__(512) void k_L2Es(
    const unsigned short* __restrict__ s2q,
    const int* __restrict__ cnt, const uint4* __restrict__ rec,
    const float* __restrict__ Wrad2, const float* __restrict__ Wmix1,
    const float* __restrict__ w_out, const float* __restrict__ g2,
    float* __restrict__ barS2, unsigned short* __restrict__ ba1q, float* __restrict__ epart)
{
    extern __shared__ unsigned short feat[];
    int t = threadIdx.x;
    int bid = XSWZ(blockIdx.x, 256);
    int frame = bid >> 5;
    int fat = frame * N_AT;
    int abase = fat + (bid & 31) * 64;
    const uint4* src = (const uint4*)(s2q + (size_t)fat * 32);
    uint4* dst = (uint4*)feat;
#pragma unroll
    for (int it = 0; it < 16; ++it) dst[t + it * 512] = src[t + it * 512];
    int g = t >> 5, c = t & 31;
    h2 wr[4];
    prep_wr(Wrad2, c, wr);
    float wv[32];
#pragma unroll
    for (int d = 0; d < 32; ++d) wv[d] = Wmix1[c * 32 + d];   // Wmix1[c][d]
    float woc = w_out[c], g2c = g2[c];
    __syncthreads();

    for (int i = 0; i < 4; ++i) {
        int n = abase + g * 4 + i;
        int cn = min(cnt[n], CAP);
        int j = n * CAP, j1 = n * CAP + cn;
        float A = 0.f, S = 0.f;
        for (; j + 3 < j1; j += 4) {
            int n0, n1, n2, n3;
            uint4 b0, b1, b2, b3;
            LOADREC(j, n0, b0) LOADREC(j+1, n1, b1) LOADREC(j+2, n2, b2) LOADREC(j+3, n3, b3)
            float r0 = dot8h(b0, wr), r1 = dot8h(b1, wr), r2 = dot8h(b2, wr), r3 = dot8h(b3, wr);
            A += r0 * b2f(feat[((n0 >> 3) - fat) * 32 + c]) + r1 * b2f(feat[((n1 >> 3) - fat) * 32 + c])
               + r2 * b2f(feat[((n2 >> 3) - fat) * 32 + c]) + r3 * b2f(feat[((n3 >> 3) - fat) * 32 + c]);
            S += r0 + r1 + r2 + r3;
        }
        for (; j < j1; ++j) {
            int n0; uint4 b0;
            LOADREC(j, n0, b0)
            float rr = dot8h(b0, wr);
            A += rr * b2f(feat[((n0 >> 3) - fat) * 32 + c]);
            S += rr;
        }
        float s2n = b2f(feat[(n - fat) * 32 + c]);
        float te = s2n * woc + A * g2c;
#pragma unroll
        for (int o = 1; o <= 16; o <<= 1) te += __shfl_xor(te, o, 32);
        if (c == 0) epart[n] = te;
        float bs2 = woc + g2c * S;
        barS2[n * 32 + c] = bs2;
        float acc = 0.f;
#pragma unroll
        for (int d = 0; d < 32; ++d) acc += __shfl(bs2, d, 32) * wv[d];
        ba1q[n * 32 + c] = f2b(acc);
    }
}

// ---------------- B1F staged: barS1 -> barA0 -> pk ----------------
// pk layout: x = s1 | s2<<16 ; y = ba0 | ba1<<16
__global__ __launch_bounds__(512) void k_B1Fs(
    const unsigned short* __restrict__ ba1q, const float* __restrict__ barS2,
    const unsigned short* __restrict__ s1q, const unsigned short* __restrict__ s2q,
    const int* __restrict__ cnt, const uint4* __restrict__ rec,
    const float* __restrict__ Wrad1, const float* __restrict__ Wmix0,
    uint2* __restrict__ pk)
{
    extern __shared__ unsigned short feat[];
    int t = threadIdx.x;
    int bid = XSWZ(blockIdx.x, 256);
    int frame = bid >> 5;
    int fat = frame * N_AT;
    int abase = fat + (bid & 31) * 64;
    const uint4* src = (const uint4*)(ba1q + (size_t)fat * 32);
    uint4* dst = (uint4*)feat;
#pragma unroll
    for (int it = 0; it < 16; ++it) dst[t + it * 512] = src[t + it * 512];
    int g = t >> 5, c = t & 31;
    h2 wr[4];
    prep_wr(Wrad1, c, wr);
    float wv[32];
#pragma unroll
    for (int d = 0; d < 32; ++d) wv[d] = Wmix0[c * 32 + d];   // Wmix0[c][d]
    __syncthreads();

    for (int i = 0; i < 4; ++i) {
        int n = abase + g * 4 + i;
        int cn = min(cnt[n], CAP);
        int j = n * CAP, j1 = n * CAP + cn;
        float A = 0.f;
        for (; j + 3 < j1; j += 4) {
            int n0, n1, n2, n3;
            uint4 b0, b1, b2, b3;
            LOADREC(j, n0, b0) LOADREC(j+1, n1, b1) LOADREC(j+2, n2, b2) LOADREC(j+3, n3, b3)
            A += dot8h(b0, wr) * b2f(feat[((n0 >> 3) - fat) * 32 + c])
               + dot8h(b1, wr) * b2f(feat[((n1 >> 3) - fat) * 32 + c])
               + dot8h(b2, wr) * b2f(feat[((n2 >> 3) - fat) * 32 + c])
               + dot8h(b3, wr) * b2f(feat[((n3 >> 3) - fat) * 32 + c]);
        }
        for (; j < j1; ++j) {
            int n0; uint4 b0;
            LOADREC(j, n0, b0)
            A += dot8h(b0, wr) * b2f(feat[((n0 >> 3) - fat) * 32 + c]);
        }
        int n32c = n * 32 + c;
        float bs1 = barS2[n32c] + A;
        float acc = 0.f;
#pragma unroll
        for (int d = 0; d < 32; ++d) acc += __shfl(bs1, d, 32) * wv[d];
        uint2 v;
        v.x = (unsigned)s1q[n32c] | ((unsigned)s2q[n32c] << 16);
        v.y = (unsigned)f2b(acc)  | ((unsigned)feat[(n - fat) * 32 + c] << 16);
        pk[n32c] = v;
    }
}

// ---------------- force pass 1: r18 preloaded form, writes both visit slots ----------------
#define EPG 8   // edges per 32-lane group
__global__ __launch_bounds__(256, 4) void k_force_e(
    const uint2* __restrict__ pk, const float* __restrict__ g2,
    const uint4* __restrict__ dbq, const uint2* __restrict__ ab,
    const uint2* __restrict__ jsl,
    const float* __restrict__ W_embed, const float* __restrict__ W_rad,
    float* __restrict__ hEdr)
{
    __shared__ float We[128];
    int t = threadIdx.x;
    if (t < 128) We[t] = W_embed[t];
    int bid = XSWZ(blockIdx.x, FE / (8 * EPG));
    int g = t >> 5;
    int c = t & 31;
    h2 wr0[4], wr1[4], wr2[4];
    prep_wr(W_rad + 0 * 1024, c, wr0);
    prep_wr(W_rad + 1 * 1024, c, wr1);
    prep_wr(W_rad + 2 * 1024, c, wr2);
    float g2c = g2[c];
    __syncthreads();

    int kbase = (bid * 8 + g) * EPG;
    uint2 e2a[EPG];
#pragma unroll
    for (int kk = 0; kk < EPG; ++kk) e2a[kk] = ab[kbase + kk];
    uint2 qa[EPG], qb[EPG];
    uint4 dd[EPG];
#pragma unroll
    for (int kk = 0; kk < EPG; ++kk) {
        qa[kk] = pk[(e2a[kk].x >> 2) * 32 + c];
        qb[kk] = pk[(e2a[kk].y >> 2) * 32 + c];
        dd[kk] = dbq[kbase + kk];
    }
#pragma unroll
    for (int kk = 0; kk < EPG; ++kk) {
        int k = kbase + kk;
        uint2 e2 = e2a[kk];
        float s0a = We[(e2.x & 3) * 32 + c];
        float s0b = We[(e2.y & 3) * 32 + c];
        float dR0 = dot8h(dd[kk], wr0), dR1 = dot8h(dd[kk], wr1), dR2 = dot8h(dd[kk], wr2);
        float tc = dR0 * (blo(qa[kk].y) * s0b + blo(qb[kk].y) * s0a)
                 + dR1 * (bhi(qa[kk].y) * blo(qb[kk].x) + bhi(qb[kk].y) * blo(qa[kk].x))
                 + dR2 * g2c * (bhi(qa[kk].x) + bhi(qb[kk].x));
#pragma unroll
        for (int o = 1; o <= 16; o <<= 1) tc += __shfl_xor(tc, o, 32);
        uint2 jv = jsl[k];
        if (c == 0) hEdr[jv.x] = tc;
        else if (c == 1) hEdr[jv.y] = tc;
    }
}

// ---------------- fused: force pass 2 (fully sequential) + energy reduce ----------------
__global__ __launch_bounds__(256, 8) void k_fgat(
    const int* __restrict__ cnt, const uint4* __restrict__ rec,
    const float* __restrict__ hEdr,
    const float* __restrict__ epart, float* __restrict__ out)
{
    if (blockIdx.x >= FN / 8) {
        __shared__ float sm[256];
        int f = blockIdx.x - FN / 8, t = threadIdx.x;
        float a = 0.f;
        for (int i = t; i < N_AT; i += 256) a += epart[f * N_AT + i];
        sm[t] = a;
        __syncthreads();
        for (int s = 128; s; s >>= 1) {
            if (t < s) sm[t] += sm[t + s];
            __syncthreads();
        }
        if (t == 0) out[f] = sm[0];
        return;
    }
    int t = threadIdx.x;
    int bid = XSWZ(blockIdx.x, FN / 8);
    int g = t >> 5, lane = t & 31;
    int n = bid * 8 + g;
    int cn = min(cnt[n], CAP);
    int base = n * CAP;
    float Fx = 0.f, Fy = 0.f, Fz = 0.f;
    for (int j = base + lane; j < base + cn; j += 32) {
        uint4 r1 = rec[2 * j + 1];            // { B.w, ux|uy, uz, 0 } sign-applied
        float d = hEdr[j];
        h2 uxy = u2h2(r1.y);
        Fx += d * (float)uxy.x;
        Fy += d * (float)uxy.y;
        Fz += d * (float)u2h2(r1.z).x;
    }
#pragma unroll
    for (int o = 1; o <= 16; o <<= 1) {
        Fx += __shfl_xor(Fx, o, 32);
        Fy += __shfl_xor(Fy, o, 32);
        Fz += __shfl_xor(Fz, o, 32);
    }
    if (lane == 0) {
        out[8 + n * 3 + 0] = Fx;
        out[8 + n * 3 + 1] = Fy;
        out[8 + n * 3 + 2] = Fz;
    }
}

extern "C" void kernel_launch(void* const* d_in, const int* in_sizes, int n_in,
                              void* d_out, int out_size, void* d_ws, size_t ws_size,
                              hipStream_t stream)
{
    const float* pos     = (const float*)d_in[0];
    const int*   eidx    = (const int*)  d_in[1];
    const float* cell    = (const float*)d_in[2];
    const int*   at      = (const int*)  d_in[3];
    const float* W_embed = (const float*)d_in[4];
    const float* W_rad   = (const float*)d_in[5];
    const float* W_mix   = (const float*)d_in[6];
    const float* w_out   = (const float*)d_in[7];
    const int*   co      = (const int*)  d_in[8];

    char* p = (char*)d_ws;
    auto carve = [&](size_t bytes) -> char* {
        char* r = p;
        p += (bytes + 255) & ~(size_t)255;
        return r;
    };
    uint4*          dbq    = (uint4*)          carve((size_t)FE * 16);
    uint2*          ab     = (uint2*)          carve((size_t)FE * 8);
    uint2*          jsl    = (uint2*)          carve((size_t)FE * 8);
    unsigned short* s1q    = (unsigned short*) carve((size_t)FN * 32 * 2);
    unsigned short* s2q    = (unsigned short*) carve((size_t)FN * 32 * 2);
    unsigned short* ba1q   = (unsigned short*) carve((size_t)FN * 32 * 2);
    float*          barS2  = (float*)          carve((size_t)FN * 32 * 4);
    uint2*          pk     = (uint2*)          carve((size_t)FN * 32 * 8);
    float*          g2     = (float*)          carve(32 * 4);
    float*          epart  = (float*)          carve((size_t)FN * 4);
    float*          hEdr   = (float*)          carve((size_t)(FN * CAP + 8) * 4);
    int*            cnt    = (int*)            carve((size_t)FN * 4);
    uint4*          rec    = (uint4*)          carve((size_t)FN * CAP * 32);

    const size_t SMEM = (size_t)N_AT * 32 * 2;   // 128 KiB frame feature table

    // prologue: zero cnt (16 blocks) + g2 (1 block)
    k_zg<<<17, 256, 0, stream>>>((int4*)cnt, w_out, W_mix + 2 * 1024, g2);

    k_edges<<<FE / 256, 256, 0, stream>>>(pos, eidx, cell, co, at, dbq, ab, jsl, cnt, rec);

    // forward
    k_L0<<<FN / 64, 512, 0, stream>>>(W_embed, s1q, cnt, rec,
                                      W_rad + 0 * 1024, W_mix + 0 * 1024, at);
    k_L1s<<<256, 512, SMEM, stream>>>(s1q, s2q, cnt, rec,
                                      W_rad + 1 * 1024, W_mix + 1 * 1024);
    // layer 2 + energy partials + barS2 + barA1 (staged)
    k_L2Es<<<256, 512, SMEM, stream>>>(s2q, cnt, rec, W_rad + 2 * 1024,
                                       W_mix + 1 * 1024, w_out, g2, barS2, ba1q, epart);
    // backward l=1 + barA0 + pack (staged)
    k_B1Fs<<<256, 512, SMEM, stream>>>(ba1q, barS2, s1q, s2q, cnt, rec,
                                       W_rad + 1 * 1024, W_mix + 0 * 1024, pk);
    // forces pass 1 (r18 preloaded edge-parallel -> both visit slots)
    k_force_e<<<FE / (8 * EPG), 256, 0, stream>>>(pk, g2, dbq, ab, jsl, W_embed, W_rad, hEdr);
    // forces pass 2 (sequential) + energy reduce, fused
    k_fgat<<<FN / 8 + F_NUM, 256, 0, stream>>>(cnt, rec, hEdr, epart, (float*)d_out);
}

// Round 24
// 173.709 us; speedup vs baseline: 1.0201x; 1.0065x over previous
//
#include <hip/hip_runtime.h>
#include <math.h>

#define F_NUM 8
#define N_AT 2048
#define E_EDGE 32768
#define FE (F_NUM*E_EDGE)   // 262144 base edges
#define FN (F_NUM*N_AT)     // 16384 atoms
#define CAP 72              // per-atom incidence capacity (avg 32, Poisson)
#define PI_F 3.14159265358979f

#if defined(__has_builtin)
#if __has_builtin(__builtin_amdgcn_fdot2)
#define HAS_FDOT2 1
#endif
#endif

typedef _Float16 h2 __attribute__((ext_vector_type(2)));

// XCD-aware swizzle: frame-major work chunks land on one XCD (frame f -> XCD f)
#define XSWZ(bid, G) (((bid) & 7) * ((G) >> 3) + ((bid) >> 3))

__device__ __forceinline__ unsigned short f2b(float x) {
    unsigned int u = __float_as_uint(x);
    u += 0x8000u;
    return (unsigned short)(u >> 16);
}
__device__ __forceinline__ float blo(unsigned int u) { return __uint_as_float(u << 16); }
__device__ __forceinline__ float bhi(unsigned int u) { return __uint_as_float(u & 0xffff0000u); }
__device__ __forceinline__ float b2f(unsigned short u) { return __uint_as_float((unsigned)u << 16); }

__device__ __forceinline__ unsigned f2h(float x) {
    union { _Float16 h; unsigned short u; } cv;
    cv.h = (_Float16)x;
    return (unsigned)cv.u;
}
__device__ __forceinline__ h2 u2h2(unsigned u) {
    union { unsigned u; h2 h; } cv;
    cv.u = u;
    return cv.h;
}
__device__ __forceinline__ float dot8h(uint4 q, const h2* w) {
#ifdef HAS_FDOT2
    float a = __builtin_amdgcn_fdot2(u2h2(q.x), w[0], 0.f, false);
    a = __builtin_amdgcn_fdot2(u2h2(q.y), w[1], a, false);
    a = __builtin_amdgcn_fdot2(u2h2(q.z), w[2], a, false);
    a = __builtin_amdgcn_fdot2(u2h2(q.w), w[3], a, false);
    return a;
#else
    h2 a0 = u2h2(q.x), a1 = u2h2(q.y), a2 = u2h2(q.z), a3 = u2h2(q.w);
    return (float)a0.x*(float)w[0].x + (float)a0.y*(float)w[0].y
         + (float)a1.x*(float)w[1].x + (float)a1.y*(float)w[1].y
         + (float)a2.x*(float)w[2].x + (float)a2.y*(float)w[2].y
         + (float)a3.x*(float)w[3].x + (float)a3.y*(float)w[3].y;
#endif
}
__device__ __forceinline__ void prep_wr(const float* __restrict__ Wrad_l, int c, h2* wr) {
#pragma unroll
    for (int bb = 0; bb < 4; bb++) {
        h2 t;
        t.x = (_Float16)Wrad_l[(2*bb)   * 128 + c * 4];
        t.y = (_Float16)Wrad_l[(2*bb+1) * 128 + c * 4];
        wr[bb] = t;
    }
}

// ---------------- prologue: zero cnt (16 blocks) + compute g2 (1 block) ----------------
__global__ __launch_bounds__(256) void k_zg(
    int4* __restrict__ cnt4, const float* __restrict__ w_out,
    const float* __restrict__ Wmix2, float* __restrict__ g2)
{
    int bid = blockIdx.x;
    if (bid < 16) {
        cnt4[bid * 256 + threadIdx.x] = make_int4(0, 0, 0, 0);
    } else if (threadIdx.x < 32) {
        int c = threadIdx.x;
        float acc = 0.f;
#pragma unroll
        for (int d = 0; d < 32; d++) acc += w_out[d] * Wmix2[c * 32 + d];
        g2[c] = acc;
    }
}

// Incidence record (32 B):
//   rec[2j]   = { nb, B.x, B.y, B.z }     nb = (u<<3)|(sign<<2)|type
//   rec[2j+1] = { B.w, ux|uy, uz|0, 0 }   unit as f16x3 with visit sign PRE-APPLIED

// ---------------- edges ----------------
__global__ __launch_bounds__(256) void k_edges(
    const float* __restrict__ pos, const int* __restrict__ eidx,
    const float* __restrict__ cell, const int* __restrict__ co_p,
    const int* __restrict__ at,
    uint4* __restrict__ dbq, uint2* __restrict__ ab, uint2* __restrict__ jsl,
    int* __restrict__ cnt, uint4* __restrict__ rec)
{
    int bid = XSWZ(blockIdx.x, FE / 256);
    int k = bid * 256 + threadIdx.x;
    int f = k >> 15;
    int e = k & (E_EDGE - 1);
    int a = eidx[f * 2 * E_EDGE + e] + f * N_AT;
    int b = eidx[f * 2 * E_EDGE + E_EDGE + e] + f * N_AT;
    int ta = at[a], tb = at[b];
    float co = (float)co_p[0];

    float vec[3];
#pragma unroll
    for (int d = 0; d < 3; d++) {
        float v  = pos[3 * b + d] - pos[3 * a + d];
        float cl = cell[3 * f + d];
        float sh = cl * ((v < -co ? 1.f : 0.f) - (v > co ? 1.f : 0.f));
        vec[d] = v + sh;
    }
    float r2   = vec[0]*vec[0] + vec[1]*vec[1] + vec[2]*vec[2] + 1e-12f;
    float r    = sqrtf(r2);
    float rinv = 1.f / r;
    float ux = vec[0]*rinv, uy = vec[1]*rinv, uz = vec[2]*rinv;
    unsigned up01 = f2h(ux)  | (f2h(uy)  << 16);
    unsigned up2  = f2h(uz);
    unsigned un01 = f2h(-ux) | (f2h(-uy) << 16);
    unsigned un2  = f2h(-uz);
    ab[k] = make_uint2((unsigned)((a << 2) | ta), (unsigned)((b << 2) | tb));

    float x = r * (1.f / 6.f);           // R_MAX = 6
    float env = 0.f, denv = 0.f;
    if (x < 1.f) {
        float x2 = x*x, x3 = x2*x, x5 = x2*x3, x6 = x5*x, x7 = x6*x, x8 = x7*x;
        env  = 1.f - 28.f*x6 + 48.f*x7 - 21.f*x8;
        denv = -168.f*x5 + 336.f*x6 - 168.f*x7;
    }
    float s1, c1;
    sincosf(PI_F * x, &s1, &c1);
    float sn = s1, cn = c1;
    const float C0 = 0.57735026919f;     // sqrt(2/6)
    float bs[8], db[8];
#pragma unroll
    for (int n = 1; n <= 8; n++) {
        float kn  = (float)n * PI_F * (1.f / 6.f);
        float bes = C0 * sn * rinv;
        bs[n-1] = bes * env;
        db[n-1] = C0 * rinv * (kn * cn - sn * rinv) * env + bes * denv * (1.f / 6.f);
        float sn2 = sn * c1 + cn * s1;
        float cn2 = cn * c1 - sn * s1;
        sn = sn2; cn = cn2;
    }
    uint4 B, D;
    B.x = f2h(bs[0]) | (f2h(bs[1]) << 16);
    B.y = f2h(bs[2]) | (f2h(bs[3]) << 16);
    B.z = f2h(bs[4]) | (f2h(bs[5]) << 16);
    B.w = f2h(bs[6]) | (f2h(bs[7]) << 16);
    D.x = f2h(db[0]) | (f2h(db[1]) << 16);
    D.y = f2h(db[2]) | (f2h(db[3]) << 16);
    D.z = f2h(db[4]) | (f2h(db[5]) << 16);
    D.w = f2h(db[6]) | (f2h(db[7]) << 16);
    dbq[k] = D;

    int sa = atomicAdd(&cnt[a], 1);
    unsigned ja = (unsigned)(FN * CAP);          // dump slot on overflow
    if (sa < CAP) {
        int j = a * CAP + sa;
        ja = (unsigned)j;
        rec[2*j]     = make_uint4((unsigned)((b << 3) | tb), B.x, B.y, B.z);
        rec[2*j + 1] = make_uint4(B.w, up01, up2, 0);
    }
    int sb = atomicAdd(&cnt[b], 1);
    unsigned jb = (unsigned)(FN * CAP);
    if (sb < CAP) {
        int j = b * CAP + sb;
        jb = (unsigned)j;
        rec[2*j]     = make_uint4((unsigned)((a << 3) | 4 | ta), B.x, B.y, B.z);
        rec[2*j + 1] = make_uint4(B.w, un01, un2, 0);
    }
    jsl[k] = make_uint2(ja, jb);
}

#define LOADREC(J, NB, B)                                    \
    {                                                        \
        uint4 ra = rec[2*(J)], rb = rec[2*(J)+1];            \
        NB = (int)ra.x;                                      \
        B  = make_uint4(ra.y, ra.z, ra.w, rb.x);             \
    }

// ---------------- L0: group-walk form, LDS embed table, shuffle mix ----------------
__global__ __launch_bounds__(512) void k_L0(
    const float* __restrict__ W_embed, unsigned short* __restrict__ soq,
    const int* __restrict__ cnt, const uint4* __restrict__ rec,
    const float* __restrict__ Wrad_l, const float* __restrict__ Wmix_l,
    const int* __restrict__ at)
{
    __shared__ float We[128];
    int t = threadIdx.x;
    if (t < 128) We[t] = W_embed[t];
    int bid = XSWZ(blockIdx.x, FN / 64);
    int g = t >> 5, c = t & 31;
    int abase = bid * 64;
    h2 wr[4];
    prep_wr(Wrad_l, c, wr);
    float wv[32];
#pragma unroll
    for (int cc = 0; cc < 32; ++cc) wv[cc] = Wmix_l[cc * 32 + c];  // Wmix[cc][c]
    __syncthreads();

    for (int i = 0; i < 4; ++i) {
        int n = abase + g * 4 + i;
        int cn = min(cnt[n], CAP);
        int j = n * CAP, j1 = n * CAP + cn;
        float A = 0.f;
        for (; j + 3 < j1; j += 4) {
            int n0, n1, n2, n3;
            uint4 b0, b1, b2, b3;
            LOADREC(j, n0, b0) LOADREC(j+1, n1, b1) LOADREC(j+2, n2, b2) LOADREC(j+3, n3, b3)
            A += dot8h(b0, wr) * We[(n0 & 3) * 32 + c] + dot8h(b1, wr) * We[(n1 & 3) * 32 + c]
               + dot8h(b2, wr) * We[(n2 & 3) * 32 + c] + dot8h(b3, wr) * We[(n3 & 3) * 32 + c];
        }
        for (; j < j1; ++j) {
            int n0; uint4 b0;
            LOADREC(j, n0, b0)
            A += dot8h(b0, wr) * We[(n0 & 3) * 32 + c];
        }
        float acc = 0.f;
#pragma unroll
        for (int cc = 0; cc < 32; ++cc) acc += __shfl(A, cc, 32) * wv[cc];
        soq[n * 32 + c] = f2b(We[at[n] * 32 + c] + acc);
    }
}

// ======== STAGED WALKS: frame feature table (128 KB) in LDS; 256 blocks x 512 thr ========

// ---------------- L1 staged ----------------
__global__ __launch_bounds__(512) void k_L1s(
    const unsigned short* __restrict__ slq, unsigned short* __restrict__ soq,
    const int* __restrict__ cnt, const uint4* __restrict__ rec,
    const float* __restrict__ Wrad_l, const float* __restrict__ Wmix_l)
{
    extern __shared__ unsigned short feat[];   // 2048*32 = 128 KB
    int t = threadIdx.x;
    int bid = XSWZ(blockIdx.x, 256);
    int frame = bid >> 5;
    int fat = frame * N_AT;
    int abase = fat + (bid & 31) * 64;
    const uint4* src = (const uint4*)(slq + (size_t)fat * 32);
    uint4* dst = (uint4*)feat;
#pragma unroll
    for (int it = 0; it < 16; ++it) dst[t + it * 512] = src[t + it * 512];
    int g = t >> 5, c = t & 31;
    h2 wr[4];
    prep_wr(Wrad_l, c, wr);
    float wv[32];
#pragma unroll
    for (int cc = 0; cc < 32; ++cc) wv[cc] = Wmix_l[cc * 32 + c];  // Wmix[cc][c]
    __syncthreads();

    for (int i = 0; i < 4; ++i) {
        int n = abase + g * 4 + i;
        int cn = min(cnt[n], CAP);
        int j = n * CAP, j1 = n * CAP + cn;
        float A = 0.f;
        for (; j + 3 < j1; j += 4) {
            int n0, n1, n2, n3;
            uint4 b0, b1, b2, b3;
            LOADREC(j, n0, b0) LOADREC(j+1, n1, b1) LOADREC(j+2, n2, b2) LOADREC(j+3, n3, b3)
            float sv0 = b2f(feat[((n0 >> 3) - fat) * 32 + c]);
            float sv1 = b2f(feat[((n1 >> 3) - fat) * 32 + c]);
            float sv2 = b2f(feat[((n2 >> 3) - fat) * 32 + c]);
            float sv3 = b2f(feat[((n3 >> 3) - fat) * 32 + c]);
            A += dot8h(b0, wr) * sv0 + dot8h(b1, wr) * sv1
               + dot8h(b2, wr) * sv2 + dot8h(b3, wr) * sv3;
        }
        for (; j < j1; ++j) {
            int n0; uint4 b0;
            LOADREC(j, n0, b0)
            A += dot8h(b0, wr) * b2f(feat[((n0 >> 3) - fat) * 32 + c]);
        }
        float acc = 0.f;
#pragma unroll
        for (int cc = 0; cc < 32; ++cc) acc += __shfl(A, cc, 32) * wv[cc];
        float base_s = b2f(feat[(n - fat) * 32 + c]);
        soq[n * 32 + c] = f2b(base_s + acc);
    }
}

// ---------------- L2E staged: energy partial + barS2 + barA1 ----------------
__global__ __launch_bounds__(512) void k_L2Es(
    const unsigned short* __restrict__ s2q,
    const int* __restrict__ cnt, const uint4* __restrict__ rec,
    const float* __restrict__ Wrad2, const float* __restrict__ Wmix1,
    const float* __restrict__ w_out, const float* __restrict__ g2,
    float* __restrict__ barS2, unsigned short* __restrict__ ba1q, float* __restrict__ epart)
{
    extern __shared__ unsigned short feat[];
    int t = threadIdx.x;
    int bid = XSWZ(blockIdx.x, 256);
    int frame = bid >> 5;
    int fat = frame * N_AT;
    int abase = fat + (bid & 31) * 64;
    const uint4* src = (const uint4*)(s2q + (size_t)fat * 32);
    uint4* dst = (uint4*)feat;
#pragma unroll
    for (int it = 0; it < 16; ++it) dst[t + it * 512] = src[t + it * 512];
    int g = t >> 5, c = t & 31;
    h2 wr[4];
    prep_wr(Wrad2, c, wr);
    float wv[32];
#pragma unroll
    for (int d = 0; d < 32; ++d) wv[d] = Wmix1[c * 32 + d];   // Wmix1[c][d]
    float woc = w_out[c], g2c = g2[c];
    __syncthreads();

    for (int i = 0; i < 4; ++i) {
        int n = abase + g * 4 + i;
        int cn = min(cnt[n], CAP);
        int j = n * CAP, j1 = n * CAP + cn;
        float A = 0.f, S = 0.f;
        for (; j + 3 < j1; j += 4) {
            int n0, n1, n2, n3;
            uint4 b0, b1, b2, b3;
            LOADREC(j, n0, b0) LOADREC(j+1, n1, b1) LOADREC(j+2, n2, b2) LOADREC(j+3, n3, b3)
            float r0 = dot8h(b0, wr), r1 = dot8h(b1, wr), r2 = dot8h(b2, wr), r3 = dot8h(b3, wr);
            A += r0 * b2f(feat[((n0 >> 3) - fat) * 32 + c]) + r1 * b2f(feat[((n1 >> 3) - fat) * 32 + c])
               + r2 * b2f(feat[((n2 >> 3) - fat) * 32 + c]) + r3 * b2f(feat[((n3 >> 3) - fat) * 32 + c]);
            S += r0 + r1 + r2 + r3;
        }
        for (; j < j1; ++j) {
            int n0; uint4 b0;
            LOADREC(j, n0, b0)
            float rr = dot8h(b0, wr);
            A += rr * b2f(feat[((n0 >> 3) - fat) * 32 + c]);
            S += rr;
        }
        float s2n = b2f(feat[(n - fat) * 32 + c]);
        float te = s2n * woc + A * g2c;
#pragma unroll
        for (int o = 1; o <= 16; o <<= 1) te += __shfl_xor(te, o, 32);
        if (c == 0) epart[n] = te;
        float bs2 = woc + g2c * S;
        barS2[n * 32 + c] = bs2;
        float acc = 0.f;
#pragma unroll
        for (int d = 0; d < 32; ++d) acc += __shfl(bs2, d, 32) * wv[d];
        ba1q[n * 32 + c] = f2b(acc);
    }
}

// ---------------- B1F staged: barS1 -> barA0 -> pk ----------------
// pk layout: x = s1 | s2<<16 ; y = ba0 | ba1<<16
__global__ __launch_bounds__(512) void k_B1Fs(
    const unsigned short* __restrict__ ba1q, const float* __restrict__ barS2,
    const unsigned short* __restrict__ s1q, const unsigned short* __restrict__ s2q,
    const int* __restrict__ cnt, const uint4* __restrict__ rec,
    const float* __restrict__ Wrad1, const float* __restrict__ Wmix0,
    uint2* __restrict__ pk)
{
    extern __shared__ unsigned short feat[];
    int t = threadIdx.x;
    int bid = XSWZ(blockIdx.x, 256);
    int frame = bid >> 5;
    int fat = frame * N_AT;
    int abase = fat + (bid & 31) * 64;
    const uint4* src = (const uint4*)(ba1q + (size_t)fat * 32);
    uint4* dst = (uint4*)feat;
#pragma unroll
    for (int it = 0; it < 16; ++it) dst[t + it * 512] = src[t + it * 512];
    int g = t >> 5, c = t & 31;
    h2 wr[4];
    prep_wr(Wrad1, c, wr);
    float wv[32];
#pragma unroll
    for (int d = 0; d < 32; ++d) wv[d] = Wmix0[c * 32 + d];   // Wmix0[c][d]
    __syncthreads();

    for (int i = 0; i < 4; ++i) {
        int n = abase + g * 4 + i;
        int cn = min(cnt[n], CAP);
        int j = n * CAP, j1 = n * CAP + cn;
        float A = 0.f;
        for (; j + 3 < j1; j += 4) {
            int n0, n1, n2, n3;
            uint4 b0, b1, b2, b3;
            LOADREC(j, n0, b0) LOADREC(j+1, n1, b1) LOADREC(j+2, n2, b2) LOADREC(j+3, n3, b3)
            A += dot8h(b0, wr) * b2f(feat[((n0 >> 3) - fat) * 32 + c])
               + dot8h(b1, wr) * b2f(feat[((n1 >> 3) - fat) * 32 + c])
               + dot8h(b2, wr) * b2f(feat[((n2 >> 3) - fat) * 32 + c])
               + dot8h(b3, wr) * b2f(feat[((n3 >> 3) - fat) * 32 + c]);
        }
        for (; j < j1; ++j) {
            int n0; uint4 b0;
            LOADREC(j, n0, b0)
            A += dot8h(b0, wr) * b2f(feat[((n0 >> 3) - fat) * 32 + c]);
        }
        int n32c = n * 32 + c;
        float bs1 = barS2[n32c] + A;
        float acc = 0.f;
#pragma unroll
        for (int d = 0; d < 32; ++d) acc += __shfl(bs1, d, 32) * wv[d];
        uint2 v;
        v.x = (unsigned)s1q[n32c] | ((unsigned)s2q[n32c] << 16);
        v.y = (unsigned)f2b(acc)  | ((unsigned)feat[(n - fat) * 32 + c] << 16);
        pk[n32c] = v;
    }
}

// ---------------- force pass 1: LDS-staged pk slice (8 channels), partial dEdr per slice ----------------
// grid: 256 blocks = 8 frames x 4 slices x 8 chunks; 512 thr; 128 KB LDS
#define FEPB (E_EDGE / 8)    // 4096 edges per block
__global__ __launch_bounds__(512) void k_force_s(
    const uint2* __restrict__ pk, const float* __restrict__ g2,
    const uint4* __restrict__ dbq, const uint2* __restrict__ ab,
    const float* __restrict__ W_embed, const float* __restrict__ W_rad,
    float* __restrict__ pEdr)
{
    extern __shared__ uint2 feat2[];     // [2048][8] = 128 KB
    __shared__ float We[128];
    int t = threadIdx.x;
    if (t < 128) We[t] = W_embed[t];
    int bid = XSWZ(blockIdx.x, 256);
    int frame = bid >> 5;
    int rem = bid & 31;
    int s = rem >> 3;                    // channel slice 0..3
    int h = rem & 7;                     // edge chunk 0..7
    int fat = frame * N_AT;
    // stage pk slice: channels [8s, 8s+8) of every atom in the frame
    for (int r = 0; r < 32; ++r) {
        int n = r * 64 + (t >> 3);
        feat2[n * 8 + (t & 7)] = pk[(size_t)(fat + n) * 32 + s * 8 + (t & 7)];
    }
    int cl = t & 7;                      // channel-in-slice
    int c = s * 8 + cl;                  // global channel
    int esub = (t >> 3) & 3;             // edge within quad
    int grp = t >> 5;                    // 16 groups
    h2 wr0[4], wr1[4], wr2[4];
    prep_wr(W_rad + 0 * 1024, c, wr0);
    prep_wr(W_rad + 1 * 1024, c, wr1);
    prep_wr(W_rad + 2 * 1024, c, wr2);
    float g2c = g2[c];
    __syncthreads();

    int kbase = frame * E_EDGE + h * FEPB + grp * (FEPB / 16);
    for (int i = 0; i < FEPB / 16 / 4; ++i) {
        int k = kbase + i * 4 + esub;
        uint2 e2 = ab[k];                            // broadcast within 8-lane set
        uint4 d  = dbq[k];
        int an = (int)(e2.x >> 2) - fat;
        int bn = (int)(e2.y >> 2) - fat;
        uint2 qa = feat2[an * 8 + cl];
        uint2 qb = feat2[bn * 8 + cl];
        float s0a = We[(e2.x & 3) * 32 + c];
        float s0b = We[(e2.y & 3) * 32 + c];
        float dR0 = dot8h(d, wr0), dR1 = dot8h(d, wr1), dR2 = dot8h(d, wr2);
        float tc = dR0 * (blo(qa.y) * s0b + blo(qb.y) * s0a)
                 + dR1 * (bhi(qa.y) * blo(qb.x) + bhi(qb.y) * blo(qa.x))
                 + dR2 * g2c * (bhi(qa.x) + bhi(qb.x));
#pragma unroll
        for (int o = 1; o <= 4; o <<= 1) tc += __shfl_xor(tc, o, 32);   // reduce the 8 channel lanes
        if (cl == 0) pEdr[(size_t)k * 4 + s] = tc;
    }
}

// ---------------- force combine: sum 4 slice partials, scatter to both visit slots ----------------
__global__ __launch_bounds__(256) void k_comb(
    const float4* __restrict__ pEdr4, const uint2* __restrict__ jsl,
    float* __restrict__ hEdr)
{
    int k = blockIdx.x * 256 + threadIdx.x;
    float4 p = pEdr4[k];
    float tc = (p.x + p.y) + (p.z + p.w);
    uint2 jv = jsl[k];
    hEdr[jv.x] = tc;
    hEdr[jv.y] = tc;
}

// ---------------- fused: force pass 2 (fully sequential) + energy reduce ----------------
__global__ __launch_bounds__(256, 8) void k_fgat(
    const int* __restrict__ cnt, const uint4* __restrict__ rec,
    const float* __restrict__ hEdr,
    const float* __restrict__ epart, float* __restrict__ out)
{
    if (blockIdx.x >= FN / 8) {
        __shared__ float sm[256];
        int f = blockIdx.x - FN / 8, t = threadIdx.x;
        float a = 0.f;
        for (int i = t; i < N_AT; i += 256) a += epart[f * N_AT + i];
        sm[t] = a;
        __syncthreads();
        for (int s = 128; s; s >>= 1) {
            if (t < s) sm[t] += sm[t + s];
            __syncthreads();
        }
        if (t == 0) out[f] = sm[0];
        return;
    }
    int t = threadIdx.x;
    int bid = XSWZ(blockIdx.x, FN / 8);
    int g = t >> 5, lane = t & 31;
    int n = bid * 8 + g;
    int cn = min(cnt[n], CAP);
    int base = n * CAP;
    float Fx = 0.f, Fy = 0.f, Fz = 0.f;
    for (int j = base + lane; j < base + cn; j += 32) {
        uint4 r1 = rec[2 * j + 1];            // { B.w, ux|uy, uz, 0 } sign-applied
        float d = hEdr[j];
        h2 uxy = u2h2(r1.y);
        Fx += d * (float)uxy.x;
        Fy += d * (float)uxy.y;
        Fz += d * (float)u2h2(r1.z).x;
    }
#pragma unroll
    for (int o = 1; o <= 16; o <<= 1) {
        Fx += __shfl_xor(Fx, o, 32);
        Fy += __shfl_xor(Fy, o, 32);
        Fz += __shfl_xor(Fz, o, 32);
    }
    if (lane == 0) {
        out[8 + n * 3 + 0] = Fx;
        out[8 + n * 3 + 1] = Fy;
        out[8 + n * 3 + 2] = Fz;
    }
}

extern "C" void kernel_launch(void* const* d_in, const int* in_sizes, int n_in,
                              void* d_out, int out_size, void* d_ws, size_t ws_size,
                              hipStream_t stream)
{
    const float* pos     = (const float*)d_in[0];
    const int*   eidx    = (const int*)  d_in[1];
    const float* cell    = (const float*)d_in[2];
    const int*   at      = (const int*)  d_in[3];
    const float* W_embed = (const float*)d_in[4];
    const float* W_rad   = (const float*)d_in[5];
    const float* W_mix   = (const float*)d_in[6];
    const float* w_out   = (const float*)d_in[7];
    const int*   co      = (const int*)  d_in[8];

    char* p = (char*)d_ws;
    auto carve = [&](size_t bytes) -> char* {
        char* r = p;
        p += (bytes + 255) & ~(size_t)255;
        return r;
    };
    uint4*          dbq    = (uint4*)          carve((size_t)FE * 16);
    uint2*          ab     = (uint2*)          carve((size_t)FE * 8);
    uint2*          jsl    = (uint2*)          carve((size_t)FE * 8);
    unsigned short* s1q    = (unsigned short*) carve((size_t)FN * 32 * 2);
    unsigned short* s2q    = (unsigned short*) carve((size_t)FN * 32 * 2);
    unsigned short* ba1q   = (unsigned short*) carve((size_t)FN * 32 * 2);
    float*          barS2  = (float*)          carve((size_t)FN * 32 * 4);
    uint2*          pk     = (uint2*)          carve((size_t)FN * 32 * 8);
    float*          g2     = (float*)          carve(32 * 4);
    float*          epart  = (float*)          carve((size_t)FN * 4);
    float*          hEdr   = (float*)          carve((size_t)(FN * CAP + 8) * 4);
    float*          pEdr   = (float*)          carve((size_t)FE * 4 * 4);
    int*            cnt    = (int*)            carve((size_t)FN * 4);
    uint4*          rec    = (uint4*)          carve((size_t)FN * CAP * 32);

    const size_t SMEM = (size_t)N_AT * 32 * 2;   // 128 KiB frame feature table

    // prologue: zero cnt (16 blocks) + g2 (1 block)
    k_zg<<<17, 256, 0, stream>>>((int4*)cnt, w_out, W_mix + 2 * 1024, g2);

    k_edges<<<FE / 256, 256, 0, stream>>>(pos, eidx, cell, co, at, dbq, ab, jsl, cnt, rec);

    // forward
    k_L0<<<FN / 64, 512, 0, stream>>>(W_embed, s1q, cnt, rec,
                                      W_rad + 0 * 1024, W_mix + 0 * 1024, at);
    k_L1s<<<256, 512, SMEM, stream>>>(s1q, s2q, cnt, rec,
                                      W_rad + 1 * 1024, W_mix + 1 * 1024);
    // layer 2 + energy partials + barS2 + barA1 (staged)
    k_L2Es<<<256, 512, SMEM, stream>>>(s2q, cnt, rec, W_rad + 2 * 1024,
                                       W_mix + 1 * 1024, w_out, g2, barS2, ba1q, epart);
    // backward l=1 + barA0 + pack (staged)
    k_B1Fs<<<256, 512, SMEM, stream>>>(ba1q, barS2, s1q, s2q, cnt, rec,
                                       W_rad + 1 * 1024, W_mix + 0 * 1024, pk);
    // forces pass 1 (LDS-staged channel-sliced partial dEdr)
    k_force_s<<<256, 512, SMEM, stream>>>(pk, g2, dbq, ab, W_embed, W_rad, pEdr);
    // combine partials + scatter to visit slots
    k_comb<<<FE / 256, 256, 0, stream>>>((const float4*)pEdr, jsl, hEdr);
    // forces pass 2 (sequential) + energy reduce, fused
    k_fgat<<<FN / 8 + F_NUM, 256, 0, stream>>>(cnt, rec, hEdr, epart, (float*)d_out);
}

// Round 25
// 167.994 us; speedup vs baseline: 1.0549x; 1.0340x over previous
//
#include <hip/hip_runtime.h>
#include <math.h>

#define F_NUM 8
#define N_AT 2048
#define E_EDGE 32768
#define FE (F_NUM*E_EDGE)   // 262144 base edges
#define FN (F_NUM*N_AT)     // 16384 atoms
#define CAP 72              // per-atom incidence capacity (avg 32, Poisson)
#define PI_F 3.14159265358979f

#if defined(__has_builtin)
#if __has_builtin(__builtin_amdgcn_fdot2)
#define HAS_FDOT2 1
#endif
#endif

typedef _Float16 h2 __attribute__((ext_vector_type(2)));

// XCD-aware swizzle: frame-major work chunks land on one XCD (frame f -> XCD f)
#define XSWZ(bid, G) (((bid) & 7) * ((G) >> 3) + ((bid) >> 3))

__device__ __forceinline__ unsigned short f2b(float x) {
    unsigned int u = __float_as_uint(x);
    u += 0x8000u;
    return (unsigned short)(u >> 16);
}
__device__ __forceinline__ float blo(unsigned int u) { return __uint_as_float(u << 16); }
__device__ __forceinline__ float bhi(unsigned int u) { return __uint_as_float(u & 0xffff0000u); }
__device__ __forceinline__ float b2f(unsigned short u) { return __uint_as_float((unsigned)u << 16); }

__device__ __forceinline__ unsigned f2h(float x) {
    union { _Float16 h; unsigned short u; } cv;
    cv.h = (_Float16)x;
    return (unsigned)cv.u;
}
__device__ __forceinline__ h2 u2h2(unsigned u) {
    union { unsigned u; h2 h; } cv;
    cv.u = u;
    return cv.h;
}
__device__ __forceinline__ float dot8h(uint4 q, const h2* w) {
#ifdef HAS_FDOT2
    float a = __builtin_amdgcn_fdot2(u2h2(q.x), w[0], 0.f, false);
    a = __builtin_amdgcn_fdot2(u2h2(q.y), w[1], a, false);
    a = __builtin_amdgcn_fdot2(u2h2(q.z), w[2], a, false);
    a = __builtin_amdgcn_fdot2(u2h2(q.w), w[3], a, false);
    return a;
#else
    h2 a0 = u2h2(q.x), a1 = u2h2(q.y), a2 = u2h2(q.z), a3 = u2h2(q.w);
    return (float)a0.x*(float)w[0].x + (float)a0.y*(float)w[0].y
         + (float)a1.x*(float)w[1].x + (float)a1.y*(float)w[1].y
         + (float)a2.x*(float)w[2].x + (float)a2.y*(float)w[2].y
         + (float)a3.x*(float)w[3].x + (float)a3.y*(float)w[3].y;
#endif
}
__device__ __forceinline__ void prep_wr(const float* __restrict__ Wrad_l, int c, h2* wr) {
#pragma unroll
    for (int bb = 0; bb < 4; bb++) {
        h2 t;
        t.x = (_Float16)Wrad_l[(2*bb)   * 128 + c * 4];
        t.y = (_Float16)Wrad_l[(2*bb+1) * 128 + c * 4];
        wr[bb] = t;
    }
}

// ---------------- prologue: zero cnt (16 blocks) + compute g2 (1 block) ----------------
__global__ __launch_bounds__(256) void k_zg(
    int4* __restrict__ cnt4, const float* __restrict__ w_out,
    const float* __restrict__ Wmix2, float* __restrict__ g2)
{
    int bid = blockIdx.x;
    if (bid < 16) {
        cnt4[bid * 256 + threadIdx.x] = make_int4(0, 0, 0, 0);
    } else if (threadIdx.x < 32) {
        int c = threadIdx.x;
        float acc = 0.f;
#pragma unroll
        for (int d = 0; d < 32; d++) acc += w_out[d] * Wmix2[c * 32 + d];
        g2[c] = acc;
    }
}

// Incidence record (32 B):
//   rec[2j]   = { nb, B.x, B.y, B.z }     nb = (u<<3)|(sign<<2)|type
//   rec[2j+1] = { B.w, ux|uy, uz|0, 0 }   unit as f16x3 with visit sign PRE-APPLIED

// ---------------- edges ----------------
__global__ __launch_bounds__(256) void k_edges(
    const float* __restrict__ pos, const int* __restrict__ eidx,
    const float* __restrict__ cell, const int* __restrict__ co_p,
    const int* __restrict__ at,
    uint4* __restrict__ dbq, uint2* __restrict__ ab, uint2* __restrict__ jsl,
    int* __restrict__ cnt, uint4* __restrict__ rec)
{
    int bid = XSWZ(blockIdx.x, FE / 256);
    int k = bid * 256 + threadIdx.x;
    int f = k >> 15;
    int e = k & (E_EDGE - 1);
    int a = eidx[f * 2 * E_EDGE + e] + f * N_AT;
    int b = eidx[f * 2 * E_EDGE + E_EDGE + e] + f * N_AT;
    int ta = at[a], tb = at[b];
    float co = (float)co_p[0];

    float vec[3];
#pragma unroll
    for (int d = 0; d < 3; d++) {
        float v  = pos[3 * b + d] - pos[3 * a + d];
        float cl = cell[3 * f + d];
        float sh = cl * ((v < -co ? 1.f : 0.f) - (v > co ? 1.f : 0.f));
        vec[d] = v + sh;
    }
    float r2   = vec[0]*vec[0] + vec[1]*vec[1] + vec[2]*vec[2] + 1e-12f;
    float r    = sqrtf(r2);
    float rinv = 1.f / r;
    float ux = vec[0]*rinv, uy = vec[1]*rinv, uz = vec[2]*rinv;
    unsigned up01 = f2h(ux)  | (f2h(uy)  << 16);
    unsigned up2  = f2h(uz);
    unsigned un01 = f2h(-ux) | (f2h(-uy) << 16);
    unsigned un2  = f2h(-uz);
    ab[k] = make_uint2((unsigned)((a << 2) | ta), (unsigned)((b << 2) | tb));

    float x = r * (1.f / 6.f);           // R_MAX = 6
    float env = 0.f, denv = 0.f;
    if (x < 1.f) {
        float x2 = x*x, x3 = x2*x, x5 = x2*x3, x6 = x5*x, x7 = x6*x, x8 = x7*x;
        env  = 1.f - 28.f*x6 + 48.f*x7 - 21.f*x8;
        denv = -168.f*x5 + 336.f*x6 - 168.f*x7;
    }
    float s1, c1;
    sincosf(PI_F * x, &s1, &c1);
    float sn = s1, cn = c1;
    const float C0 = 0.57735026919f;     // sqrt(2/6)
    float bs[8], db[8];
#pragma unroll
    for (int n = 1; n <= 8; n++) {
        float kn  = (float)n * PI_F * (1.f / 6.f);
        float bes = C0 * sn * rinv;
        bs[n-1] = bes * env;
        db[n-1] = C0 * rinv * (kn * cn - sn * rinv) * env + bes * denv * (1.f / 6.f);
        float sn2 = sn * c1 + cn * s1;
        float cn2 = cn * c1 - sn * s1;
        sn = sn2; cn = cn2;
    }
    uint4 B, D;
    B.x = f2h(bs[0]) | (f2h(bs[1]) << 16);
    B.y = f2h(bs[2]) | (f2h(bs[3]) << 16);
    B.z = f2h(bs[4]) | (f2h(bs[5]) << 16);
    B.w = f2h(bs[6]) | (f2h(bs[7]) << 16);
    D.x = f2h(db[0]) | (f2h(db[1]) << 16);
    D.y = f2h(db[2]) | (f2h(db[3]) << 16);
    D.z = f2h(db[4]) | (f2h(db[5]) << 16);
    D.w = f2h(db[6]) | (f2h(db[7]) << 16);
    dbq[k] = D;

    int sa = atomicAdd(&cnt[a], 1);
    unsigned ja = (unsigned)(FN * CAP);          // dump slot on overflow
    if (sa < CAP) {
        int j = a * CAP + sa;
        ja = (unsigned)j;
        rec[2*j]     = make_uint4((unsigned)((b << 3) | tb), B.x, B.y, B.z);
        rec[2*j + 1] = make_uint4(B.w, up01, up2, 0);
    }
    int sb = atomicAdd(&cnt[b], 1);
    unsigned jb = (unsigned)(FN * CAP);
    if (sb < CAP) {
        int j = b * CAP + sb;
        jb = (unsigned)j;
        rec[2*j]     = make_uint4((unsigned)((a << 3) | 4 | ta), B.x, B.y, B.z);
        rec[2*j + 1] = make_uint4(B.w, un01, un2, 0);
    }
    jsl[k] = make_uint2(ja, jb);
}

#define LOADREC(J, NB, B)                                    \
    {                                                        \
        uint4 ra = rec[2*(J)], rb = rec[2*(J)+1];            \
        NB = (int)ra.x;                                      \
        B  = make_uint4(ra.y, ra.z, ra.w, rb.x);             \
    }

// ---------------- L0: group-walk form, LDS embed table, shuffle mix ----------------
__global__ __launch_bounds__(512) void k_L0(
    const float* __restrict__ W_embed, unsigned short* __restrict__ soq,
    const int* __restrict__ cnt, const uint4* __restrict__ rec,
    const float* __restrict__ Wrad_l, const float* __restrict__ Wmix_l,
    const int* __restrict__ at)
{
    __shared__ float We[128];
    int t = threadIdx.x;
    if (t < 128) We[t] = W_embed[t];
    int bid = XSWZ(blockIdx.x, FN / 64);
    int g = t >> 5, c = t & 31;
    int abase = bid * 64;
    h2 wr[4];
    prep_wr(Wrad_l, c, wr);
    float wv[32];
#pragma unroll
    for (int cc = 0; cc < 32; ++cc) wv[cc] = Wmix_l[cc * 32 + c];  // Wmix[cc][c]
    __syncthreads();

    for (int i = 0; i < 4; ++i) {
        int n = abase + g * 4 + i;
        int cn = min(cnt[n], CAP);
        int j = n * CAP, j1 = n * CAP + cn;
        float A = 0.f;
        for (; j + 3 < j1; j += 4) {
            int n0, n1, n2, n3;
            uint4 b0, b1, b2, b3;
            LOADREC(j, n0, b0) LOADREC(j+1, n1, b1) LOADREC(j+2, n2, b2) LOADREC(j+3, n3, b3)
            A += dot8h(b0, wr) * We[(n0 & 3) * 32 + c] + dot8h(b1, wr) * We[(n1 & 3) * 32 + c]
               + dot8h(b2, wr) * We[(n2 & 3) * 32 + c] + dot8h(b3, wr) * We[(n3 & 3) * 32 + c];
        }
        for (; j < j1; ++j) {
            int n0; uint4 b0;
            LOADREC(j, n0, b0)
            A += dot8h(b0, wr) * We[(n0 & 3) * 32 + c];
        }
        float acc = 0.f;
#pragma unroll
        for (int cc = 0; cc < 32; ++cc) acc += __shfl(A, cc, 32) * wv[cc];
        soq[n * 32 + c] = f2b(We[at[n] * 32 + c] + acc);
    }
}

// ======== STAGED WALKS: frame feature table (128 KB) in LDS; 256 blocks x 512 thr ========

// ---------------- L1 staged ----------------
__global__ __launch_bounds__(512) void k_L1s(
    const unsigned short* __restrict__ slq, unsigned short* __restrict__ soq,
    const int* __restrict__ cnt, const uint4* __restrict__ rec,
    const float* __restrict__ Wrad_l, const float* __restrict__ Wmix_l)
{
    extern __shared__ unsigned short feat[];   // 2048*32 = 128 KB
    int t = threadIdx.x;
    int bid = XSWZ(blockIdx.x, 256);
    int frame = bid >> 5;
    int fat = frame * N_AT;
    int abase = fat + (bid & 31) * 64;
    const uint4* src = (const uint4*)(slq + (size_t)fat * 32);
    uint4* dst = (uint4*)feat;
#pragma unroll
    for (int it = 0; it < 16; ++it) dst[t + it * 512] = src[t + it * 512];
    int g = t >> 5, c = t & 31;
    h2 wr[4];
    prep_wr(Wrad_l, c, wr);
    float wv[32];
#pragma unroll
    for (int cc = 0; cc < 32; ++cc) wv[cc] = Wmix_l[cc * 32 + c];  // Wmix[cc][c]
    __syncthreads();

    for (int i = 0; i < 4; ++i) {
        int n = abase + g * 4 + i;
        int cn = min(cnt[n], CAP);
        int j = n * CAP, j1 = n * CAP + cn;
        float A = 0.f;
        for (; j + 3 < j1; j += 4) {
            int n0, n1, n2, n3;
            uint4 b0, b1, b2, b3;
            LOADREC(j, n0, b0) LOADREC(j+1, n1, b1) LOADREC(j+2, n2, b2) LOADREC(j+3, n3, b3)
            float sv0 = b2f(feat[((n0 >> 3) - fat) * 32 + c]);
            float sv1 = b2f(feat[((n1 >> 3) - fat) * 32 + c]);
            float sv2 = b2f(feat[((n2 >> 3) - fat) * 32 + c]);
            float sv3 = b2f(feat[((n3 >> 3) - fat) * 32 + c]);
            A += dot8h(b0, wr) * sv0 + dot8h(b1, wr) * sv1
               + dot8h(b2, wr) * sv2 + dot8h(b3, wr) * sv3;
        }
        for (; j < j1; ++j) {
            int n0; uint4 b0;
            LOADREC(j, n0, b0)
            A += dot8h(b0, wr) * b2f(feat[((n0 >> 3) - fat) * 32 + c]);
        }
        float acc = 0.f;
#pragma unroll
        for (int cc = 0; cc < 32; ++cc) acc += __shfl(A, cc, 32) * wv[cc];
        float base_s = b2f(feat[(n - fat) * 32 + c]);
        soq[n * 32 + c] = f2b(base_s + acc);
    }
}

// ---------------- L2E staged: energy partial + barS2 + barA1 ----------------
__global__ __launch_bounds__(512) void k_L2Es(
    const unsigned short* __restrict__ s2q,
    const int* __restrict__ cnt, const uint4* __restrict__ rec,
    const float* __restrict__ Wrad2, const float* __restrict__ Wmix1,
    const float* __restrict__ w_out, const float* __restrict__ g2,
    float* __restrict__ barS2, unsigned short* __restrict__ ba1q, float* __restrict__ epart)
{
    extern __shared__ unsigned short feat[];
    int t = threadIdx.x;
    int bid = XSWZ(blockIdx.x, 256);
    int frame = bid >> 5;
    int fat = frame * N_AT;
    int abase = fat + (bid & 31) * 64;
    const uint4* src = (const uint4*)(s2q + (size_t)fat * 32);
    uint4* dst = (uint4*)feat;
#pragma unroll
    for (int it = 0; it < 16; ++it) dst[t + it * 512] = src[t + it * 512];
    int g = t >> 5, c = t & 31;
    h2 wr[4];
    prep_wr(Wrad2, c, wr);
    float wv[32];
#pragma unroll
    for (int d = 0; d < 32; ++d) wv[d] = Wmix1[c * 32 + d];   // Wmix1[c][d]
    float woc = w_out[c], g2c = g2[c];
    __syncthreads();

    for (int i = 0; i < 4; ++i) {
        int n = abase + g * 4 + i;
        int cn = min(cnt[n], CAP);
        int j = n * CAP, j1 = n * CAP + cn;
        float A = 0.f, S = 0.f;
        for (; j + 3 < j1; j += 4) {
            int n0, n1, n2, n3;
            uint4 b0, b1, b2, b3;
            LOADREC(j, n0, b0) LOADREC(j+1, n1, b1) LOADREC(j+2, n2, b2) LOADREC(j+3, n3, b3)
            float r0 = dot8h(b0, wr), r1 = dot8h(b1, wr), r2 = dot8h(b2, wr), r3 = dot8h(b3, wr);
            A += r0 * b2f(feat[((n0 >> 3) - fat) * 32 + c]) + r1 * b2f(feat[((n1 >> 3) - fat) * 32 + c])
               + r2 * b2f(feat[((n2 >> 3) - fat) * 32 + c]) + r3 * b2f(feat[((n3 >> 3) - fat) * 32 + c]);
            S += r0 + r1 + r2 + r3;
        }
        for (; j < j1; ++j) {
            int n0; uint4 b0;
            LOADREC(j, n0, b0)
            float rr = dot8h(b0, wr);
            A += rr * b2f(feat[((n0 >> 3) - fat) * 32 + c]);
            S += rr;
        }
        float s2n = b2f(feat[(n - fat) * 32 + c]);
        float te = s2n * woc + A * g2c;
#pragma unroll
        for (int o = 1; o <= 16; o <<= 1) te += __shfl_xor(te, o, 32);
        if (c == 0) epart[n] = te;
        float bs2 = woc + g2c * S;
        barS2[n * 32 + c] = bs2;
        float acc = 0.f;
#pragma unroll
        for (int d = 0; d < 32; ++d) acc += __shfl(bs2, d, 32) * wv[d];
        ba1q[n * 32 + c] = f2b(acc);
    }
}

// ---------------- B1F staged: barS1 -> barA0 -> pk ----------------
// pk layout: x = s1 | s2<<16 ; y = ba0 | ba1<<16
__global__ __launch_bounds__(512) void k_B1Fs(
    const unsigned short* __restrict__ ba1q, const float* __restrict__ barS2,
    const unsigned short* __restrict__ s1q, const unsigned short* __restrict__ s2q,
    const int* __restrict__ cnt, const uint4* __restrict__ rec,
    const float* __restrict__ Wrad1, const float* __restrict__ Wmix0,
    uint2* __restrict__ pk)
{
    extern __shared__ unsigned short feat[];
    int t = threadIdx.x;
    int bid = XSWZ(blockIdx.x, 256);
    int frame = bid >> 5;
    int fat = frame * N_AT;
    int abase = fat + (bid & 31) * 64;
    const uint4* src = (const uint4*)(ba1q + (size_t)fat * 32);
    uint4* dst = (uint4*)feat;
#pragma unroll
    for (int it = 0; it < 16; ++it) dst[t + it * 512] = src[t + it * 512];
    int g = t >> 5, c = t & 31;
    h2 wr[4];
    prep_wr(Wrad1, c, wr);
    float wv[32];
#pragma unroll
    for (int d = 0; d < 32; ++d) wv[d] = Wmix0[c * 32 + d];   // Wmix0[c][d]
    __syncthreads();

    for (int i = 0; i < 4; ++i) {
        int n = abase + g * 4 + i;
        int cn = min(cnt[n], CAP);
        int j = n * CAP, j1 = n * CAP + cn;
        float A = 0.f;
        for (; j + 3 < j1; j += 4) {
            int n0, n1, n2, n3;
            uint4 b0, b1, b2, b3;
            LOADREC(j, n0, b0) LOADREC(j+1, n1, b1) LOADREC(j+2, n2, b2) LOADREC(j+3, n3, b3)
            A += dot8h(b0, wr) * b2f(feat[((n0 >> 3) - fat) * 32 + c])
               + dot8h(b1, wr) * b2f(feat[((n1 >> 3) - fat) * 32 + c])
               + dot8h(b2, wr) * b2f(feat[((n2 >> 3) - fat) * 32 + c])
               + dot8h(b3, wr) * b2f(feat[((n3 >> 3) - fat) * 32 + c]);
        }
        for (; j < j1; ++j) {
            int n0; uint4 b0;
            LOADREC(j, n0, b0)
            A += dot8h(b0, wr) * b2f(feat[((n0 >> 3) - fat) * 32 + c]);
        }
        int n32c = n * 32 + c;
        float bs1 = barS2[n32c] + A;
        float acc = 0.f;
#pragma unroll
        for (int d = 0; d < 32; ++d) acc += __shfl(bs1, d, 32) * wv[d];
        uint2 v;
        v.x = (unsigned)s1q[n32c] | ((unsigned)s2q[n32c] << 16);
        v.y = (unsigned)f2b(acc)  | ((unsigned)feat[(n - fat) * 32 + c] << 16);
        pk[n32c] = v;
    }
}

// ---------------- force pass 1: LDS-staged pk slice, 4-edge preloaded unroll ----------------
// grid: 256 blocks = 8 frames x 4 slices x 8 chunks; 512 thr; 128 KB LDS
#define FEPB (E_EDGE / 8)    // 4096 edges per block
__global__ __launch_bounds__(512) void k_force_s(
    const uint2* __restrict__ pk, const float* __restrict__ g2,
    const uint4* __restrict__ dbq, const uint2* __restrict__ ab,
    const float* __restrict__ W_embed, const float* __restrict__ W_rad,
    float* __restrict__ pEdr)
{
    extern __shared__ uint2 feat2[];     // [2048][8] = 128 KB
    __shared__ float We[128];
    int t = threadIdx.x;
    if (t < 128) We[t] = W_embed[t];
    int bid = XSWZ(blockIdx.x, 256);
    int frame = bid >> 5;
    int rem = bid & 31;
    int s = rem >> 3;                    // channel slice 0..3
    int h = rem & 7;                     // edge chunk 0..7
    int fat = frame * N_AT;
    // stage pk slice: channels [8s, 8s+8) of every atom in the frame
    for (int r = 0; r < 32; ++r) {
        int n = r * 64 + (t >> 3);
        feat2[n * 8 + (t & 7)] = pk[(size_t)(fat + n) * 32 + s * 8 + (t & 7)];
    }
    int cl = t & 7;                      // channel-in-slice
    int c = s * 8 + cl;                  // global channel
    int esub = (t >> 3) & 3;             // edge within quad
    int grp = t >> 5;                    // 16 groups
    h2 wr0[4], wr1[4], wr2[4];
    prep_wr(W_rad + 0 * 1024, c, wr0);
    prep_wr(W_rad + 1 * 1024, c, wr1);
    prep_wr(W_rad + 2 * 1024, c, wr2);
    float g2c = g2[c];
    __syncthreads();

    int kbase = frame * E_EDGE + h * FEPB + grp * (FEPB / 16);
    // 4x unrolled: preload ab/dbq for 4 edges (stride 4 within the group's range)
    for (int i = 0; i < FEPB / 16 / 16; ++i) {         // 16 outer iterations
        int k0 = kbase + i * 16 + esub;
        uint2 e0 = ab[k0],      e1 = ab[k0 + 4],  e2 = ab[k0 + 8],  e3 = ab[k0 + 12];
        uint4 d0 = dbq[k0],     d1 = dbq[k0 + 4], d2 = dbq[k0 + 8], d3 = dbq[k0 + 12];
        uint2 qa0 = feat2[((int)(e0.x >> 2) - fat) * 8 + cl];
        uint2 qb0 = feat2[((int)(e0.y >> 2) - fat) * 8 + cl];
        uint2 qa1 = feat2[((int)(e1.x >> 2) - fat) * 8 + cl];
        uint2 qb1 = feat2[((int)(e1.y >> 2) - fat) * 8 + cl];
        uint2 qa2 = feat2[((int)(e2.x >> 2) - fat) * 8 + cl];
        uint2 qb2 = feat2[((int)(e2.y >> 2) - fat) * 8 + cl];
        uint2 qa3 = feat2[((int)(e3.x >> 2) - fat) * 8 + cl];
        uint2 qb3 = feat2[((int)(e3.y >> 2) - fat) * 8 + cl];
#define FBODY(EK, E2, DD, QA, QB)                                              \
        {                                                                      \
            float s0a = We[(E2.x & 3) * 32 + c];                               \
            float s0b = We[(E2.y & 3) * 32 + c];                               \
            float dR0 = dot8h(DD, wr0), dR1 = dot8h(DD, wr1), dR2 = dot8h(DD, wr2); \
            float tc = dR0 * (blo(QA.y) * s0b + blo(QB.y) * s0a)               \
                     + dR1 * (bhi(QA.y) * blo(QB.x) + bhi(QB.y) * blo(QA.x))   \
                     + dR2 * g2c * (bhi(QA.x) + bhi(QB.x));                    \
            _Pragma("unroll")                                                  \
            for (int o = 1; o <= 4; o <<= 1) tc += __shfl_xor(tc, o, 32);      \
            if (cl == 0) pEdr[(size_t)(EK) * 4 + s] = tc;                      \
        }
        FBODY(k0,      e0, d0, qa0, qb0)
        FBODY(k0 + 4,  e1, d1, qa1, qb1)
        FBODY(k0 + 8,  e2, d2, qa2, qb2)
        FBODY(k0 + 12, e3, d3, qa3, qb3)
#undef FBODY
    }
}

// ---------------- force combine: sum 4 slice partials, scatter to both visit slots ----------------
__global__ __launch_bounds__(256) void k_comb(
    const float4* __restrict__ pEdr4, const uint2* __restrict__ jsl,
    float* __restrict__ hEdr)
{
    int k = blockIdx.x * 256 + threadIdx.x;
    float4 p = pEdr4[k];
    float tc = (p.x + p.y) + (p.z + p.w);
    uint2 jv = jsl[k];
    hEdr[jv.x] = tc;
    hEdr[jv.y] = tc;
}

// ---------------- fused: force pass 2 (fully sequential) + energy reduce ----------------
__global__ __launch_bounds__(256, 8) void k_fgat(
    const int* __restrict__ cnt, const uint4* __restrict__ rec,
    const float* __restrict__ hEdr,
    const float* __restrict__ epart, float* __restrict__ out)
{
    if (blockIdx.x >= FN / 8) {
        __shared__ float sm[256];
        int f = blockIdx.x - FN / 8, t = threadIdx.x;
        float a = 0.f;
        for (int i = t; i < N_AT; i += 256) a += epart[f * N_AT + i];
        sm[t] = a;
        __syncthreads();
        for (int s = 128; s; s >>= 1) {
            if (t < s) sm[t] += sm[t + s];
            __syncthreads();
        }
        if (t == 0) out[f] = sm[0];
        return;
    }
    int t = threadIdx.x;
    int bid = XSWZ(blockIdx.x, FN / 8);
    int g = t >> 5, lane = t & 31;
    int n = bid * 8 + g;
    int cn = min(cnt[n], CAP);
    int base = n * CAP;
    float Fx = 0.f, Fy = 0.f, Fz = 0.f;
    for (int j = base + lane; j < base + cn; j += 32) {
        uint4 r1 = rec[2 * j + 1];            // { B.w, ux|uy, uz, 0 } sign-applied
        float d = hEdr[j];
        h2 uxy = u2h2(r1.y);
        Fx += d * (float)uxy.x;
        Fy += d * (float)uxy.y;
        Fz += d * (float)u2h2(r1.z).x;
    }
#pragma unroll
    for (int o = 1; o <= 16; o <<= 1) {
        Fx += __shfl_xor(Fx, o, 32);
        Fy += __shfl_xor(Fy, o, 32);
        Fz += __shfl_xor(Fz, o, 32);
    }
    if (lane == 0) {
        out[8 + n * 3 + 0] = Fx;
        out[8 + n * 3 + 1] = Fy;
        out[8 + n * 3 + 2] = Fz;
    }
}

extern "C" void kernel_launch(void* const* d_in, const int* in_sizes, int n_in,
                              void* d_out, int out_size, void* d_ws, size_t ws_size,
                              hipStream_t stream)
{
    const float* pos     = (const float*)d_in[0];
    const int*   eidx    = (const int*)  d_in[1];
    const float* cell    = (const float*)d_in[2];
    const int*   at      = (const int*)  d_in[3];
    const float* W_embed = (const float*)d_in[4];
    const float* W_rad   = (const float*)d_in[5];
    const float* W_mix   = (const float*)d_in[6];
    const float* w_out   = (const float*)d_in[7];
    const int*   co      = (const int*)  d_in[8];

    char* p = (char*)d_ws;
    auto carve = [&](size_t bytes) -> char* {
        char* r = p;
        p += (bytes + 255) & ~(size_t)255;
        return r;
    };
    uint4*          dbq    = (uint4*)          carve((size_t)FE * 16);
    uint2*          ab     = (uint2*)          carve((size_t)FE * 8);
    uint2*          jsl    = (uint2*)          carve((size_t)FE * 8);
    unsigned short* s1q    = (unsigned short*) carve((size_t)FN * 32 * 2);
    unsigned short* s2q    = (unsigned short*) carve((size_t)FN * 32 * 2);
    unsigned short* ba1q   = (unsigned short*) carve((size_t)FN * 32 * 2);
    float*          barS2  = (float*)          carve((size_t)FN * 32 * 4);
    uint2*          pk     = (uint2*)          carve((size_t)FN * 32 * 8);
    float*          g2     = (float*)          carve(32 * 4);
    float*          epart  = (float*)          carve((size_t)FN * 4);
    float*          hEdr   = (float*)          carve((size_t)(FN * CAP + 8) * 4);
    float*          pEdr   = (float*)          carve((size_t)FE * 4 * 4);
    int*            cnt    = (int*)            carve((size_t)FN * 4);
    uint4*          rec    = (uint4*)          carve((size_t)FN * CAP * 32);

    const size_t SMEM = (size_t)N_AT * 32 * 2;   // 128 KiB frame feature table

    // prologue: zero cnt (16 blocks) + g2 (1 block)
    k_zg<<<17, 256, 0, stream>>>((int4*)cnt, w_out, W_mix + 2 * 1024, g2);

    k_edges<<<FE / 256, 256, 0, stream>>>(pos, eidx, cell, co, at, dbq, ab, jsl, cnt, rec);

    // forward
    k_L0<<<FN / 64, 512, 0, stream>>>(W_embed, s1q, cnt, rec,
                                      W_rad + 0 * 1024, W_mix + 0 * 1024, at);
    k_L1s<<<256, 512, SMEM, stream>>>(s1q, s2q, cnt, rec,
                                      W_rad + 1 * 1024, W_mix + 1 * 1024);
    // layer 2 + energy partials + barS2 + barA1 (staged)
    k_L2Es<<<256, 512, SMEM, stream>>>(s2q, cnt, rec, W_rad + 2 * 1024,
                                       W_mix + 1 * 1024, w_out, g2, barS2, ba1q, epart);
    // backward l=1 + barA0 + pack (staged)
    k_B1Fs<<<256, 512, SMEM, stream>>>(ba1q, barS2, s1q, s2q, cnt, rec,
                                       W_rad + 1 * 1024, W_mix + 0 * 1024, pk);
    // forces pass 1 (LDS-staged channel-sliced partial dEdr, 4x unrolled)
    k_force_s<<<256, 512, SMEM, stream>>>(pk, g2, dbq, ab, W_embed, W_rad, pEdr);
    // combine partials + scatter to visit slots
    k_comb<<<FE / 256, 256, 0, stream>>>((const float4*)pEdr, jsl, hEdr);
    // forces pass 2 (sequential) + energy reduce, fused
    k_fgat<<<FN / 8 + F_NUM, 256, 0, stream>>>(cnt, rec, hEdr, epart, (float*)d_out);
}

// Round 26
// 162.389 us; speedup vs baseline: 1.0913x; 1.0345x over previous
//
#include <hip/hip_runtime.h>
#include <math.h>

#define F_NUM 8
#define N_AT 2048
#define E_EDGE 32768
#define FE (F_NUM*E_EDGE)   // 262144 base edges
#define FN (F_NUM*N_AT)     // 16384 atoms
#define CAP 72              // per-atom incidence capacity (avg 32, Poisson)
#define PI_F 3.14159265358979f

#if defined(__has_builtin)
#if __has_builtin(__builtin_amdgcn_fdot2)
#define HAS_FDOT2 1
#endif
#endif

typedef _Float16 h2 __attribute__((ext_vector_type(2)));

// XCD-aware swizzle: frame-major work chunks land on one XCD (frame f -> XCD f)
#define XSWZ(bid, G) (((bid) & 7) * ((G) >> 3) + ((bid) >> 3))

__device__ __forceinline__ unsigned short f2b(float x) {
    unsigned int u = __float_as_uint(x);
    u += 0x8000u;
    return (unsigned short)(u >> 16);
}
__device__ __forceinline__ float blo(unsigned int u) { return __uint_as_float(u << 16); }
__device__ __forceinline__ float bhi(unsigned int u) { return __uint_as_float(u & 0xffff0000u); }
__device__ __forceinline__ float b2f(unsigned short u) { return __uint_as_float((unsigned)u << 16); }

__device__ __forceinline__ unsigned f2h(float x) {
    union { _Float16 h; unsigned short u; } cv;
    cv.h = (_Float16)x;
    return (unsigned)cv.u;
}
__device__ __forceinline__ h2 u2h2(unsigned u) {
    union { unsigned u; h2 h; } cv;
    cv.u = u;
    return cv.h;
}
__device__ __forceinline__ float dot8h(uint4 q, const h2* w) {
#ifdef HAS_FDOT2
    float a = __builtin_amdgcn_fdot2(u2h2(q.x), w[0], 0.f, false);
    a = __builtin_amdgcn_fdot2(u2h2(q.y), w[1], a, false);
    a = __builtin_amdgcn_fdot2(u2h2(q.z), w[2], a, false);
    a = __builtin_amdgcn_fdot2(u2h2(q.w), w[3], a, false);
    return a;
#else
    h2 a0 = u2h2(q.x), a1 = u2h2(q.y), a2 = u2h2(q.z), a3 = u2h2(q.w);
    return (float)a0.x*(float)w[0].x + (float)a0.y*(float)w[0].y
         + (float)a1.x*(float)w[1].x + (float)a1.y*(float)w[1].y
         + (float)a2.x*(float)w[2].x + (float)a2.y*(float)w[2].y
         + (float)a3.x*(float)w[3].x + (float)a3.y*(float)w[3].y;
#endif
}
__device__ __forceinline__ void prep_wr(const float* __restrict__ Wrad_l, int c, h2* wr) {
#pragma unroll
    for (int bb = 0; bb < 4; bb++) {
        h2 t;
        t.x = (_Float16)Wrad_l[(2*bb)   * 128 + c * 4];
        t.y = (_Float16)Wrad_l[(2*bb+1) * 128 + c * 4];
        wr[bb] = t;
    }
}

// ---------------- prologue: zero cnt (16 blocks) + compute g2 (1 block) ----------------
__global__ __launch_bounds__(256) void k_zg(
    int4* __restrict__ cnt4, const float* __restrict__ w_out,
    const float* __restrict__ Wmix2, float* __restrict__ g2)
{
    int bid = blockIdx.x;
    if (bid < 16) {
        cnt4[bid * 256 + threadIdx.x] = make_int4(0, 0, 0, 0);
    } else if (threadIdx.x < 32) {
        int c = threadIdx.x;
        float acc = 0.f;
#pragma unroll
        for (int d = 0; d < 32; d++) acc += w_out[d] * Wmix2[c * 32 + d];
        g2[c] = acc;
    }
}

// Incidence record (32 B):
//   rec[2j]   = { nb, B.x, B.y, B.z }     nb = (u<<3)|(sign<<2)|type
//   rec[2j+1] = { B.w, ux|uy, uz|0, 0 }   unit as f16x3 with visit sign PRE-APPLIED

// ---------------- edges ----------------
__global__ __launch_bounds__(256) void k_edges(
    const float* __restrict__ pos, const int* __restrict__ eidx,
    const float* __restrict__ cell, const int* __restrict__ co_p,
    const int* __restrict__ at,
    uint4* __restrict__ dbq, uint2* __restrict__ ab, uint2* __restrict__ jsl,
    int* __restrict__ cnt, uint4* __restrict__ rec)
{
    int bid = XSWZ(blockIdx.x, FE / 256);
    int k = bid * 256 + threadIdx.x;
    int f = k >> 15;
    int e = k & (E_EDGE - 1);
    int a = eidx[f * 2 * E_EDGE + e] + f * N_AT;
    int b = eidx[f * 2 * E_EDGE + E_EDGE + e] + f * N_AT;
    int ta = at[a], tb = at[b];
    float co = (float)co_p[0];

    float vec[3];
#pragma unroll
    for (int d = 0; d < 3; d++) {
        float v  = pos[3 * b + d] - pos[3 * a + d];
        float cl = cell[3 * f + d];
        float sh = cl * ((v < -co ? 1.f : 0.f) - (v > co ? 1.f : 0.f));
        vec[d] = v + sh;
    }
    float r2   = vec[0]*vec[0] + vec[1]*vec[1] + vec[2]*vec[2] + 1e-12f;
    float r    = sqrtf(r2);
    float rinv = 1.f / r;
    float ux = vec[0]*rinv, uy = vec[1]*rinv, uz = vec[2]*rinv;
    unsigned up01 = f2h(ux)  | (f2h(uy)  << 16);
    unsigned up2  = f2h(uz);
    unsigned un01 = f2h(-ux) | (f2h(-uy) << 16);
    unsigned un2  = f2h(-uz);
    ab[k] = make_uint2((unsigned)((a << 2) | ta), (unsigned)((b << 2) | tb));

    float x = r * (1.f / 6.f);           // R_MAX = 6
    float env = 0.f, denv = 0.f;
    if (x < 1.f) {
        float x2 = x*x, x3 = x2*x, x5 = x2*x3, x6 = x5*x, x7 = x6*x, x8 = x7*x;
        env  = 1.f - 28.f*x6 + 48.f*x7 - 21.f*x8;
        denv = -168.f*x5 + 336.f*x6 - 168.f*x7;
    }
    float s1, c1;
    sincosf(PI_F * x, &s1, &c1);
    float sn = s1, cn = c1;
    const float C0 = 0.57735026919f;     // sqrt(2/6)
    float bs[8], db[8];
#pragma unroll
    for (int n = 1; n <= 8; n++) {
        float kn  = (float)n * PI_F * (1.f / 6.f);
        float bes = C0 * sn * rinv;
        bs[n-1] = bes * env;
        db[n-1] = C0 * rinv * (kn * cn - sn * rinv) * env + bes * denv * (1.f / 6.f);
        float sn2 = sn * c1 + cn * s1;
        float cn2 = cn * c1 - sn * s1;
        sn = sn2; cn = cn2;
    }
    uint4 B, D;
    B.x = f2h(bs[0]) | (f2h(bs[1]) << 16);
    B.y = f2h(bs[2]) | (f2h(bs[3]) << 16);
    B.z = f2h(bs[4]) | (f2h(bs[5]) << 16);
    B.w = f2h(bs[6]) | (f2h(bs[7]) << 16);
    D.x = f2h(db[0]) | (f2h(db[1]) << 16);
    D.y = f2h(db[2]) | (f2h(db[3]) << 16);
    D.z = f2h(db[4]) | (f2h(db[5]) << 16);
    D.w = f2h(db[6]) | (f2h(db[7]) << 16);
    dbq[k] = D;

    int sa = atomicAdd(&cnt[a], 1);
    unsigned ja = (unsigned)(FN * CAP);          // dump slot on overflow
    if (sa < CAP) {
        int j = a * CAP + sa;
        ja = (unsigned)j;
        rec[2*j]     = make_uint4((unsigned)((b << 3) | tb), B.x, B.y, B.z);
        rec[2*j + 1] = make_uint4(B.w, up01, up2, 0);
    }
    int sb = atomicAdd(&cnt[b], 1);
    unsigned jb = (unsigned)(FN * CAP);
    if (sb < CAP) {
        int j = b * CAP + sb;
        jb = (unsigned)j;
        rec[2*j]     = make_uint4((unsigned)((a << 3) | 4 | ta), B.x, B.y, B.z);
        rec[2*j + 1] = make_uint4(B.w, un01, un2, 0);
    }
    jsl[k] = make_uint2(ja, jb);
}

#define LOADREC(J, NB, B)                                    \
    {                                                        \
        uint4 ra = rec[2*(J)], rb = rec[2*(J)+1];            \
        NB = (int)ra.x;                                      \
        B  = make_uint4(ra.y, ra.z, ra.w, rb.x);             \
    }

// ---------------- L0: group-walk form, LDS embed table, shuffle mix; 8-wide ----------------
__global__ __launch_bounds__(512) void k_L0(
    const float* __restrict__ W_embed, unsigned short* __restrict__ soq,
    const int* __restrict__ cnt, const uint4* __restrict__ rec,
    const float* __restrict__ Wrad_l, const float* __restrict__ Wmix_l,
    const int* __restrict__ at)
{
    __shared__ float We[128];
    int t = threadIdx.x;
    if (t < 128) We[t] = W_embed[t];
    int bid = XSWZ(blockIdx.x, FN / 64);
    int g = t >> 5, c = t & 31;
    int abase = bid * 64;
    h2 wr[4];
    prep_wr(Wrad_l, c, wr);
    float wv[32];
#pragma unroll
    for (int cc = 0; cc < 32; ++cc) wv[cc] = Wmix_l[cc * 32 + c];  // Wmix[cc][c]
    __syncthreads();

    for (int i = 0; i < 4; ++i) {
        int n = abase + g * 4 + i;
        int cn = min(cnt[n], CAP);
        int j = n * CAP, j1 = n * CAP + cn;
        float A = 0.f;
        for (; j + 7 < j1; j += 8) {
            int n0, n1, n2, n3, n4, n5, n6, n7;
            uint4 b0, b1, b2, b3, b4, b5, b6, b7;
            LOADREC(j, n0, b0) LOADREC(j+1, n1, b1) LOADREC(j+2, n2, b2) LOADREC(j+3, n3, b3)
            LOADREC(j+4, n4, b4) LOADREC(j+5, n5, b5) LOADREC(j+6, n6, b6) LOADREC(j+7, n7, b7)
            A += dot8h(b0, wr) * We[(n0 & 3) * 32 + c] + dot8h(b1, wr) * We[(n1 & 3) * 32 + c]
               + dot8h(b2, wr) * We[(n2 & 3) * 32 + c] + dot8h(b3, wr) * We[(n3 & 3) * 32 + c]
               + dot8h(b4, wr) * We[(n4 & 3) * 32 + c] + dot8h(b5, wr) * We[(n5 & 3) * 32 + c]
               + dot8h(b6, wr) * We[(n6 & 3) * 32 + c] + dot8h(b7, wr) * We[(n7 & 3) * 32 + c];
        }
        for (; j + 3 < j1; j += 4) {
            int n0, n1, n2, n3;
            uint4 b0, b1, b2, b3;
            LOADREC(j, n0, b0) LOADREC(j+1, n1, b1) LOADREC(j+2, n2, b2) LOADREC(j+3, n3, b3)
            A += dot8h(b0, wr) * We[(n0 & 3) * 32 + c] + dot8h(b1, wr) * We[(n1 & 3) * 32 + c]
               + dot8h(b2, wr) * We[(n2 & 3) * 32 + c] + dot8h(b3, wr) * We[(n3 & 3) * 32 + c];
        }
        for (; j < j1; ++j) {
            int n0; uint4 b0;
            LOADREC(j, n0, b0)
            A += dot8h(b0, wr) * We[(n0 & 3) * 32 + c];
        }
        float acc = 0.f;
#pragma unroll
        for (int cc = 0; cc < 32; ++cc) acc += __shfl(A, cc, 32) * wv[cc];
        soq[n * 32 + c] = f2b(We[at[n] * 32 + c] + acc);
    }
}

// ======== STAGED WALKS: frame feature table (128 KB) in LDS; 256 blocks x 512 thr ========

// ---------------- L1 staged; 8-wide ----------------
__global__ __launch_bounds__(512) void k_L1s(
    const unsigned short* __restrict__ slq, unsigned short* __restrict__ soq,
    const int* __restrict__ cnt, const uint4* __restrict__ rec,
    const float* __restrict__ Wrad_l, const float* __restrict__ Wmix_l)
{
    extern __shared__ unsigned short feat[];   // 2048*32 = 128 KB
    int t = threadIdx.x;
    int bid = XSWZ(blockIdx.x, 256);
    int frame = bid >> 5;
    int fat = frame * N_AT;
    int abase = fat + (bid & 31) * 64;
    const uint4* src = (const uint4*)(slq + (size_t)fat * 32);
    uint4* dst = (uint4*)feat;
#pragma unroll
    for (int it = 0; it < 16; ++it) dst[t + it * 512] = src[t + it * 512];
    int g = t >> 5, c = t & 31;
    h2 wr[4];
    prep_wr(Wrad_l, c, wr);
    float wv[32];
#pragma unroll
    for (int cc = 0; cc < 32; ++cc) wv[cc] = Wmix_l[cc * 32 + c];  // Wmix[cc][c]
    __syncthreads();

    for (int i = 0; i < 4; ++i) {
        int n = abase + g * 4 + i;
        int cn = min(cnt[n], CAP);
        int j = n * CAP, j1 = n * CAP + cn;
        float A = 0.f;
        for (; j + 7 < j1; j += 8) {
            int n0, n1, n2, n3, n4, n5, n6, n7;
            uint4 b0, b1, b2, b3, b4, b5, b6, b7;
            LOADREC(j, n0, b0) LOADREC(j+1, n1, b1) LOADREC(j+2, n2, b2) LOADREC(j+3, n3, b3)
            LOADREC(j+4, n4, b4) LOADREC(j+5, n5, b5) LOADREC(j+6, n6, b6) LOADREC(j+7, n7, b7)
            float sv0 = b2f(feat[((n0 >> 3) - fat) * 32 + c]);
            float sv1 = b2f(feat[((n1 >> 3) - fat) * 32 + c]);
            float sv2 = b2f(feat[((n2 >> 3) - fat) * 32 + c]);
            float sv3 = b2f(feat[((n3 >> 3) - fat) * 32 + c]);
            float sv4 = b2f(feat[((n4 >> 3) - fat) * 32 + c]);
            float sv5 = b2f(feat[((n5 >> 3) - fat) * 32 + c]);
            float sv6 = b2f(feat[((n6 >> 3) - fat) * 32 + c]);
            float sv7 = b2f(feat[((n7 >> 3) - fat) * 32 + c]);
            A += dot8h(b0, wr) * sv0 + dot8h(b1, wr) * sv1
               + dot8h(b2, wr) * sv2 + dot8h(b3, wr) * sv3
               + dot8h(b4, wr) * sv4 + dot8h(b5, wr) * sv5
               + dot8h(b6, wr) * sv6 + dot8h(b7, wr) * sv7;
        }
        for (; j + 3 < j1; j += 4) {
            int n0, n1, n2, n3;
            uint4 b0, b1, b2, b3;
            LOADREC(j, n0, b0) LOADREC(j+1, n1, b1) LOADREC(j+2, n2, b2) LOADREC(j+3, n3, b3)
            float sv0 = b2f(feat[((n0 >> 3) - fat) * 32 + c]);
            float sv1 = b2f(feat[((n1 >> 3) - fat) * 32 + c]);
            float sv2 = b2f(feat[((n2 >> 3) - fat) * 32 + c]);
            float sv3 = b2f(feat[((n3 >> 3) - fat) * 32 + c]);
            A += dot8h(b0, wr) * sv0 + dot8h(b1, wr) * sv1
               + dot8h(b2, wr) * sv2 + dot8h(b3, wr) * sv3;
        }
        for (; j < j1; ++j) {
            int n0; uint4 b0;
            LOADREC(j, n0, b0)
            A += dot8h(b0, wr) * b2f(feat[((n0 >> 3) - fat) * 32 + c]);
        }
        float acc = 0.f;
#pragma unroll
        for (int cc = 0; cc < 32; ++cc) acc += __shfl(A, cc, 32) * wv[cc];
        float base_s = b2f(feat[(n - fat) * 32 + c]);
        soq[n * 32 + c] = f2b(base_s + acc);
    }
}

// ---------------- L2E staged: energy partial + barS2 + barA1; 8-wide ----------------
__global__ __launch_bounds__(512) void k_L2Es(
    const unsigned short* __restrict__ s2q,
    const int* __restrict__ cnt, const uint4* __restrict__ rec,
    const float* __restrict__ Wrad2, const float* __restrict__ Wmix1,
    const float* __restrict__ w_out, const float* __restrict__ g2,
    float* __restrict__ barS2, unsigned short* __restrict__ ba1q, float* __restrict__ epart)
{
    extern __shared__ unsigned short feat[];
    int t = threadIdx.x;
    int bid = XSWZ(blockIdx.x, 256);
    int frame = bid >> 5;
    int fat = frame * N_AT;
    int abase = fat + (bid & 31) * 64;
    const uint4* src = (const uint4*)(s2q + (size_t)fat * 32);
    uint4* dst = (uint4*)feat;
#pragma unroll
    for (int it = 0; it < 16; ++it) dst[t + it * 512] = src[t + it * 512];
    int g = t >> 5, c = t & 31;
    h2 wr[4];
    prep_wr(Wrad2, c, wr);
    float wv[32];
#pragma unroll
    for (int d = 0; d < 32; ++d) wv[d] = Wmix1[c * 32 + d];   // Wmix1[c][d]
    float woc = w_out[c], g2c = g2[c];
    __syncthreads();

    for (int i = 0; i < 4; ++i) {
        int n = abase + g * 4 + i;
        int cn = min(cnt[n], CAP);
        int j = n * CAP, j1 = n * CAP + cn;
        float A = 0.f, S = 0.f;
        for (; j + 7 < j1; j += 8) {
            int n0, n1, n2, n3, n4, n5, n6, n7;
            uint4 b0, b1, b2, b3, b4, b5, b6, b7;
            LOADREC(j, n0, b0) LOADREC(j+1, n1, b1) LOADREC(j+2, n2, b2) LOADREC(j+3, n3, b3)
            LOADREC(j+4, n4, b4) LOADREC(j+5, n5, b5) LOADREC(j+6, n6, b6) LOADREC(j+7, n7, b7)
            float r0 = dot8h(b0, wr), r1 = dot8h(b1, wr), r2 = dot8h(b2, wr), r3 = dot8h(b3, wr);
            float r4 = dot8h(b4, wr), r5 = dot8h(b5, wr), r6 = dot8h(b6, wr), r7 = dot8h(b7, wr);
            A += r0 * b2f(feat[((n0 >> 3) - fat) * 32 + c]) + r1 * b2f(feat[((n1 >> 3) - fat) * 32 + c])
               + r2 * b2f(feat[((n2 >> 3) - fat) * 32 + c]) + r3 * b2f(feat[((n3 >> 3) - fat) * 32 + c])
               + r4 * b2f(feat[((n4 >> 3) - fat) * 32 + c]) + r5 * b2f(feat[((n5 >> 3) - fat) * 32 + c])
               + r6 * b2f(feat[((n6 >> 3) - fat) * 32 + c]) + r7 * b2f(feat[((n7 >> 3) - fat) * 32 + c]);
            S += (r0 + r1 + r2 + r3) + (r4 + r5 + r6 + r7);
        }
        for (; j + 3 < j1; j += 4) {
            int n0, n1, n2, n3;
            uint4 b0, b1, b2, b3;
            LOADREC(j, n0, b0) LOADREC(j+1, n1, b1) LOADREC(j+2, n2, b2) LOADREC(j+3, n3, b3)
            float r0 = dot8h(b0, wr), r1 = dot8h(b1, wr), r2 = dot8h(b2, wr), r3 = dot8h(b3, wr);
            A += r0 * b2f(feat[((n0 >> 3) - fat) * 32 + c]) + r1 * b2f(feat[((n1 >> 3) - fat) * 32 + c])
               + r2 * b2f(feat[((n2 >> 3) - fat) * 32 + c]) + r3 * b2f(feat[((n3 >> 3) - fat) * 32 + c]);
            S += r0 + r1 + r2 + r3;
        }
        for (; j < j1; ++j) {
            int n0; uint4 b0;
            LOADREC(j, n0, b0)
            float rr = dot8h(b0, wr);
            A += rr * b2f(feat[((n0 >> 3) - fat) * 32 + c]);
            S += rr;
        }
        float s2n = b2f(feat[(n - fat) * 32 + c]);
        float te = s2n * woc + A * g2c;
#pragma unroll
        for (int o = 1; o <= 16; o <<= 1) te += __shfl_xor(te, o, 32);
        if (c == 0) epart[n] = te;
        float bs2 = woc + g2c * S;
        barS2[n * 32 + c] = bs2;
        float acc = 0.f;
#pragma unroll
        for (int d = 0; d < 32; ++d) acc += __shfl(bs2, d, 32) * wv[d];
        ba1q[n * 32 + c] = f2b(acc);
    }
}

// ---------------- B1F staged: barS1 -> barA0 -> pk; 8-wide ----------------
// pk layout: x = s1 | s2<<16 ; y = ba0 | ba1<<16
__global__ __launch_bounds__(512) void k_B1Fs(
    const unsigned short* __restrict__ ba1q, const float* __restrict__ barS2,
    const unsigned short* __restrict__ s1q, const unsigned short* __restrict__ s2q,
    const int* __restrict__ cnt, const uint4* __restrict__ rec,
    const float* __restrict__ Wrad1, const float* __restrict__ Wmix0,
    uint2* __restrict__ pk)
{
    extern __shared__ unsigned short feat[];
    int t = threadIdx.x;
    int bid = XSWZ(blockIdx.x, 256);
    int frame = bid >> 5;
    int fat = frame * N_AT;
    int abase = fat + (bid & 31) * 64;
    const uint4* src = (const uint4*)(ba1q + (size_t)fat * 32);
    uint4* dst = (uint4*)feat;
#pragma unroll
    for (int it = 0; it < 16; ++it) dst[t + it * 512] = src[t + it * 512];
    int g = t >> 5, c = t & 31;
    h2 wr[4];
    prep_wr(Wrad1, c, wr);
    float wv[32];
#pragma unroll
    for (int d = 0; d < 32; ++d) wv[d] = Wmix0[c * 32 + d];   // Wmix0[c][d]
    __syncthreads();

    for (int i = 0; i < 4; ++i) {
        int n = abase + g * 4 + i;
        int cn = min(cnt[n], CAP);
        int j = n * CAP, j1 = n * CAP + cn;
        float A = 0.f;
        for (; j + 7 < j1; j += 8) {
            int n0, n1, n2, n3, n4, n5, n6, n7;
            uint4 b0, b1, b2, b3, b4, b5, b6, b7;
            LOADREC(j, n0, b0) LOADREC(j+1, n1, b1) LOADREC(j+2, n2, b2) LOADREC(j+3, n3, b3)
            LOADREC(j+4, n4, b4) LOADREC(j+5, n5, b5) LOADREC(j+6, n6, b6) LOADREC(j+7, n7, b7)
            A += dot8h(b0, wr) * b2f(feat[((n0 >> 3) - fat) * 32 + c])
               + dot8h(b1, wr) * b2f(feat[((n1 >> 3) - fat) * 32 + c])
               + dot8h(b2, wr) * b2f(feat[((n2 >> 3) - fat) * 32 + c])
               + dot8h(b3, wr) * b2f(feat[((n3 >> 3) - fat) * 32 + c])
               + dot8h(b4, wr) * b2f(feat[((n4 >> 3) - fat) * 32 + c])
               + dot8h(b5, wr) * b2f(feat[((n5 >> 3) - fat) * 32 + c])
               + dot8h(b6, wr) * b2f(feat[((n6 >> 3) - fat) * 32 + c])
               + dot8h(b7, wr) * b2f(feat[((n7 >> 3) - fat) * 32 + c]);
        }
        for (; j + 3 < j1; j += 4) {
            int n0, n1, n2, n3;
            uint4 b0, b1, b2, b3;
            LOADREC(j, n0, b0) LOADREC(j+1, n1, b1) LOADREC(j+2, n2, b2) LOADREC(j+3, n3, b3)
            A += dot8h(b0, wr) * b2f(feat[((n0 >> 3) - fat) * 32 + c])
               + dot8h(b1, wr) * b2f(feat[((n1 >> 3) - fat) * 32 + c])
               + dot8h(b2, wr) * b2f(feat[((n2 >> 3) - fat) * 32 + c])
               + dot8h(b3, wr) * b2f(feat[((n3 >> 3) - fat) * 32 + c]);
        }
        for (; j < j1; ++j) {
            int n0; uint4 b0;
            LOADREC(j, n0, b0)
            A += dot8h(b0, wr) * b2f(feat[((n0 >> 3) - fat) * 32 + c]);
        }
        int n32c = n * 32 + c;
        float bs1 = barS2[n32c] + A;
        float acc = 0.f;
#pragma unroll
        for (int d = 0; d < 32; ++d) acc += __shfl(bs1, d, 32) * wv[d];
        uint2 v;
        v.x = (unsigned)s1q[n32c] | ((unsigned)s2q[n32c] << 16);
        v.y = (unsigned)f2b(acc)  | ((unsigned)feat[(n - fat) * 32 + c] << 16);
        pk[n32c] = v;
    }
}

// ---------------- force pass 1: LDS-staged pk slice, 8-edge preloaded unroll ----------------
// grid: 256 blocks = 8 frames x 4 slices x 8 chunks; 512 thr; 128 KB LDS
#define FEPB (E_EDGE / 8)    // 4096 edges per block
__global__ __launch_bounds__(512) void k_force_s(
    const uint2* __restrict__ pk, const float* __restrict__ g2,
    const uint4* __restrict__ dbq, const uint2* __restrict__ ab,
    const float* __restrict__ W_embed, const float* __restrict__ W_rad,
    float* __restrict__ pEdr)
{
    extern __shared__ uint2 feat2[];     // [2048][8] = 128 KB
    __shared__ float We[128];
    int t = threadIdx.x;
    if (t < 128) We[t] = W_embed[t];
    int bid = XSWZ(blockIdx.x, 256);
    int frame = bid >> 5;
    int rem = bid & 31;
    int s = rem >> 3;                    // channel slice 0..3
    int h = rem & 7;                     // edge chunk 0..7
    int fat = frame * N_AT;
    // stage pk slice: channels [8s, 8s+8) of every atom in the frame
    for (int r = 0; r < 32; ++r) {
        int n = r * 64 + (t >> 3);
        feat2[n * 8 + (t & 7)] = pk[(size_t)(fat + n) * 32 + s * 8 + (t & 7)];
    }
    int cl = t & 7;                      // channel-in-slice
    int c = s * 8 + cl;                  // global channel
    int esub = (t >> 3) & 3;             // edge within quad
    int grp = t >> 5;                    // 16 groups
    h2 wr0[4], wr1[4], wr2[4];
    prep_wr(W_rad + 0 * 1024, c, wr0);
    prep_wr(W_rad + 1 * 1024, c, wr1);
    prep_wr(W_rad + 2 * 1024, c, wr2);
    float g2c = g2[c];
    __syncthreads();

    int kbase = frame * E_EDGE + h * FEPB + grp * (FEPB / 16);
    // 8x unrolled: preload ab/dbq + LDS gathers for 8 edges (stride 4 within group range)
    for (int i = 0; i < FEPB / 16 / 32; ++i) {         // 8 outer iterations
        int k0 = kbase + i * 32 + esub;
        uint2 e0 = ab[k0],      e1 = ab[k0 + 4],  e2 = ab[k0 + 8],  e3 = ab[k0 + 12];
        uint2 e4 = ab[k0 + 16], e5 = ab[k0 + 20], e6 = ab[k0 + 24], e7 = ab[k0 + 28];
        uint4 d0 = dbq[k0],      d1 = dbq[k0 + 4],  d2 = dbq[k0 + 8],  d3 = dbq[k0 + 12];
        uint4 d4 = dbq[k0 + 16], d5 = dbq[k0 + 20], d6 = dbq[k0 + 24], d7 = dbq[k0 + 28];
        uint2 qa0 = feat2[((int)(e0.x >> 2) - fat) * 8 + cl];
        uint2 qb0 = feat2[((int)(e0.y >> 2) - fat) * 8 + cl];
        uint2 qa1 = feat2[((int)(e1.x >> 2) - fat) * 8 + cl];
        uint2 qb1 = feat2[((int)(e1.y >> 2) - fat) * 8 + cl];
        uint2 qa2 = feat2[((int)(e2.x >> 2) - fat) * 8 + cl];
        uint2 qb2 = feat2[((int)(e2.y >> 2) - fat) * 8 + cl];
        uint2 qa3 = feat2[((int)(e3.x >> 2) - fat) * 8 + cl];
        uint2 qb3 = feat2[((int)(e3.y >> 2) - fat) * 8 + cl];
        uint2 qa4 = feat2[((int)(e4.x >> 2) - fat) * 8 + cl];
        uint2 qb4 = feat2[((int)(e4.y >> 2) - fat) * 8 + cl];
        uint2 qa5 = feat2[((int)(e5.x >> 2) - fat) * 8 + cl];
        uint2 qb5 = feat2[((int)(e5.y >> 2) - fat) * 8 + cl];
        uint2 qa6 = feat2[((int)(e6.x >> 2) - fat) * 8 + cl];
        uint2 qb6 = feat2[((int)(e6.y >> 2) - fat) * 8 + cl];
        uint2 qa7 = feat2[((int)(e7.x >> 2) - fat) * 8 + cl];
        uint2 qb7 = feat2[((int)(e7.y >> 2) - fat) * 8 + cl];
#define FBODY(EK, E2, DD, QA, QB)                                              \
        {                                                                      \
            float s0a = We[(E2.x & 3) * 32 + c];                               \
            float s0b = We[(E2.y & 3) * 32 + c];                               \
            float dR0 = dot8h(DD, wr0), dR1 = dot8h(DD, wr1), dR2 = dot8h(DD, wr2); \
            float tc = dR0 * (blo(QA.y) * s0b + blo(QB.y) * s0a)               \
                     + dR1 * (bhi(QA.y) * blo(QB.x) + bhi(QB.y) * blo(QA.x))   \
                     + dR2 * g2c * (bhi(QA.x) + bhi(QB.x));                    \
            _Pragma("unroll")                                                  \
            for (int o = 1; o <= 4; o <<= 1) tc += __shfl_xor(tc, o, 32);      \
            if (cl == 0) pEdr[(size_t)(EK) * 4 + s] = tc;                      \
        }
        FBODY(k0,      e0, d0, qa0, qb0)
        FBODY(k0 + 4,  e1, d1, qa1, qb1)
        FBODY(k0 + 8,  e2, d2, qa2, qb2)
        FBODY(k0 + 12, e3, d3, qa3, qb3)
        FBODY(k0 + 16, e4, d4, qa4, qb4)
        FBODY(k0 + 20, e5, d5, qa5, qb5)
        FBODY(k0 + 24, e6, d6, qa6, qb6)
        FBODY(k0 + 28, e7, d7, qa7, qb7)
#undef FBODY
    }
}

// ---------------- force combine: sum 4 slice partials, scatter to both visit slots ----------------
__global__ __launch_bounds__(256) void k_comb(
    const float4* __restrict__ pEdr4, const uint2* __restrict__ jsl,
    float* __restrict__ hEdr)
{
    int k = blockIdx.x * 256 + threadIdx.x;
    float4 p = pEdr4[k];
    float tc = (p.x + p.y) + (p.z + p.w);
    uint2 jv = jsl[k];
    hEdr[jv.x] = tc;
    hEdr[jv.y] = tc;
}

// ---------------- fused: force pass 2 (fully sequential) + energy reduce ----------------
__global__ __launch_bounds__(256, 8) void k_fgat(
    const int* __restrict__ cnt, const uint4* __restrict__ rec,
    const float* __restrict__ hEdr,
    const float* __restrict__ epart, float* __restrict__ out)
{
    if (blockIdx.x >= FN / 8) {
        __shared__ float sm[256];
        int f = blockIdx.x - FN / 8, t = threadIdx.x;
        float a = 0.f;
        for (int i = t; i < N_AT; i += 256) a += epart[f * N_AT + i];
        sm[t] = a;
        __syncthreads();
        for (int s = 128; s; s >>= 1) {
            if (t < s) sm[t] += sm[t + s];
            __syncthreads();
        }
        if (t == 0) out[f] = sm[0];
        return;
    }
    int t = threadIdx.x;
    int bid = XSWZ(blockIdx.x, FN / 8);
    int g = t >> 5, lane = t & 31;
    int n = bid * 8 + g;
    int cn = min(cnt[n], CAP);
    int base = n * CAP;
    float Fx = 0.f, Fy = 0.f, Fz = 0.f;
    for (int j = base + lane; j < base + cn; j += 32) {
        uint4 r1 = rec[2 * j + 1];            // { B.w, ux|uy, uz, 0 } sign-applied
        float d = hEdr[j];
        h2 uxy = u2h2(r1.y);
        Fx += d * (float)uxy.x;
        Fy += d * (float)uxy.y;
        Fz += d * (float)u2h2(r1.z).x;
    }
#pragma unroll
    for (int o = 1; o <= 16; o <<= 1) {
        Fx += __shfl_xor(Fx, o, 32);
        Fy += __shfl_xor(Fy, o, 32);
        Fz += __shfl_xor(Fz, o, 32);
    }
    if (lane == 0) {
        out[8 + n * 3 + 0] = Fx;
        out[8 + n * 3 + 1] = Fy;
        out[8 + n * 3 + 2] = Fz;
    }
}

extern "C" void kernel_launch(void* const* d_in, const int* in_sizes, int n_in,
                              void* d_out, int out_size, void* d_ws, size_t ws_size,
                              hipStream_t stream)
{
    const float* pos     = (const float*)d_in[0];
    const int*   eidx    = (const int*)  d_in[1];
    const float* cell    = (const float*)d_in[2];
    const int*   at      = (const int*)  d_in[3];
    const float* W_embed = (const float*)d_in[4];
    const float* W_rad   = (const float*)d_in[5];
    const float* W_mix   = (const float*)d_in[6];
    const float* w_out   = (const float*)d_in[7];
    const int*   co      = (const int*)  d_in[8];

    char* p = (char*)d_ws;
    auto carve = [&](size_t bytes) -> char* {
        char* r = p;
        p += (bytes + 255) & ~(size_t)255;
        return r;
    };
    uint4*          dbq    = (uint4*)          carve((size_t)FE * 16);
    uint2*          ab     = (uint2*)          carve((size_t)FE * 8);
    uint2*          jsl    = (uint2*)          carve((size_t)FE * 8);
    unsigned short* s1q    = (unsigned short*) carve((size_t)FN * 32 * 2);
    unsigned short* s2q    = (unsigned short*) carve((size_t)FN * 32 * 2);
    unsigned short* ba1q   = (unsigned short*) carve((size_t)FN * 32 * 2);
    float*          barS2  = (float*)          carve((size_t)FN * 32 * 4);
    uint2*          pk     = (uint2*)          carve((size_t)FN * 32 * 8);
    float*          g2     = (float*)          carve(32 * 4);
    float*          epart  = (float*)          carve((size_t)FN * 4);
    float*          hEdr   = (float*)          carve((size_t)(FN * CAP + 8) * 4);
    float*          pEdr   = (float*)          carve((size_t)FE * 4 * 4);
    int*            cnt    = (int*)            carve((size_t)FN * 4);
    uint4*          rec    = (uint4*)          carve((size_t)FN * CAP * 32);

    const size_t SMEM = (size_t)N_AT * 32 * 2;   // 128 KiB frame feature table

    // prologue: zero cnt (16 blocks) + g2 (1 block)
    k_zg<<<17, 256, 0, stream>>>((int4*)cnt, w_out, W_mix + 2 * 1024, g2);

    k_edges<<<FE / 256, 256, 0, stream>>>(pos, eidx, cell, co, at, dbq, ab, jsl, cnt, rec);

    // forward
    k_L0<<<FN / 64, 512, 0, stream>>>(W_embed, s1q, cnt, rec,
                                      W_rad + 0 * 1024, W_mix + 0 * 1024, at);
    k_L1s<<<256, 512, SMEM, stream>>>(s1q, s2q, cnt, rec,
                                      W_rad + 1 * 1024, W_mix + 1 * 1024);
    // layer 2 + energy partials + barS2 + barA1 (staged)
    k_L2Es<<<256, 512, SMEM, stream>>>(s2q, cnt, rec, W_rad + 2 * 1024,
                                       W_mix + 1 * 1024, w_out, g2, barS2, ba1q, epart);
    // backward l=1 + barA0 + pack (staged)
    k_B1Fs<<<256, 512, SMEM, stream>>>(ba1q, barS2, s1q, s2q, cnt, rec,
                                       W_rad + 1 * 1024, W_mix + 0 * 1024, pk);
    // forces pass 1 (LDS-staged channel-sliced partial dEdr, 8x unrolled)
    k_force_s<<<256, 512, SMEM, stream>>>(pk, g2, dbq, ab, W_embed, W_rad, pEdr);
    // combine partials + scatter to visit slots
    k_comb<<<FE / 256, 256, 0, stream>>>((const float4*)pEdr, jsl, hEdr);
    // forces pass 2 (sequential) + energy reduce, fused
    k_fgat<<<FN / 8 + F_NUM, 256, 0, stream>>>(cnt, rec, hEdr, epart, (float*)d_out);
}